// Round 1
// baseline (1104.782 us; speedup 1.0000x reference)
//
#include <hip/hip_runtime.h>
#include <cstdint>

typedef unsigned short u16;
typedef unsigned int u32;

#define N_TOKENS 8192
#define D_MODEL 1024
#define DIM_FF 4096
#define N_EXPERTS 8
#define MAX_SLOTS (N_TOKENS * 2)

typedef __bf16 bf16x8 __attribute__((ext_vector_type(8)));
typedef float f32x4 __attribute__((ext_vector_type(4)));

// ---------- helpers ----------
__device__ __forceinline__ u16 f2bf(float f) {
  u32 u = __float_as_uint(f);
  u32 r = (u + 0x7FFFu + ((u >> 16) & 1u)) >> 16;  // RNE
  return (u16)r;
}

// async global->LDS, 16B per lane; LDS dst = wave-uniform base + lane*16
__device__ __forceinline__ void gl2lds16(const void* g, void* l) {
  __builtin_amdgcn_global_load_lds(
      (__attribute__((address_space(1))) void*)(g),
      (__attribute__((address_space(3))) void*)(l), 16, 0, 0);
}

// ---------- gate: logits -> softmax -> top2 -> renorm ----------
__global__ __launch_bounds__(256) void gate_kernel(
    const float* __restrict__ x, const float* __restrict__ Wg,
    const float* __restrict__ bg, int* __restrict__ eidx,
    float* __restrict__ ew, int* __restrict__ counts) {
  int tok = (int)((blockIdx.x * 256 + threadIdx.x) >> 6);
  int lane = threadIdx.x & 63;
  const float* xr = x + (size_t)tok * D_MODEL;
  float acc[8] = {0.f, 0.f, 0.f, 0.f, 0.f, 0.f, 0.f, 0.f};
  for (int j = 0; j < 16; ++j) {
    int d = lane + 64 * j;
    float xv = xr[d];
    float4 wa = *(const float4*)(Wg + d * 8);
    float4 wb = *(const float4*)(Wg + d * 8 + 4);
    acc[0] += xv * wa.x; acc[1] += xv * wa.y; acc[2] += xv * wa.z; acc[3] += xv * wa.w;
    acc[4] += xv * wb.x; acc[5] += xv * wb.y; acc[6] += xv * wb.z; acc[7] += xv * wb.w;
  }
#pragma unroll
  for (int off = 32; off > 0; off >>= 1) {
#pragma unroll
    for (int e = 0; e < 8; ++e) acc[e] += __shfl_xor(acc[e], off, 64);
  }
  if (lane == 0) {
    float p[8], m = -1e30f;
#pragma unroll
    for (int e = 0; e < 8; ++e) { p[e] = acc[e] + bg[e]; m = fmaxf(m, p[e]); }
    float s = 0.f;
#pragma unroll
    for (int e = 0; e < 8; ++e) { p[e] = __expf(p[e] - m); s += p[e]; }
#pragma unroll
    for (int e = 0; e < 8; ++e) p[e] /= s;
    int i0 = 0;
#pragma unroll
    for (int e = 1; e < 8; ++e) if (p[e] > p[i0]) i0 = e;
    int i1 = (i0 == 0) ? 1 : 0;
#pragma unroll
    for (int e = 0; e < 8; ++e) if (e != i0 && p[e] > p[i1]) i1 = e;
    float denom = p[i0] + p[i1] + 1e-9f;
    eidx[2 * tok] = i0; eidx[2 * tok + 1] = i1;
    ew[2 * tok] = p[i0] / denom; ew[2 * tok + 1] = p[i1] / denom;
    atomicAdd(&counts[i0], 1);
    atomicAdd(&counts[i1], 1);
  }
}

__global__ void scan_kernel(const int* __restrict__ counts, int* __restrict__ offsets) {
  if (threadIdx.x == 0) {
    int o = 0;
    for (int e = 0; e < N_EXPERTS; ++e) { offsets[e] = o; o += counts[e]; }
    offsets[N_EXPERTS] = o;
  }
}

__global__ __launch_bounds__(256) void fill_kernel(
    const int* __restrict__ eidx, const float* __restrict__ ew,
    const int* __restrict__ offsets, int* __restrict__ fill,
    int* __restrict__ rowtok, float* __restrict__ rowwt) {
  int t = blockIdx.x * 256 + threadIdx.x;
#pragma unroll
  for (int k = 0; k < 2; ++k) {
    int e = eidx[2 * t + k];
    int pos = offsets[e] + atomicAdd(&fill[e], 1);
    rowtok[pos] = t;
    rowwt[pos] = ew[2 * t + k];
  }
}

// ---------- fp32 -> bf16 copy of x ----------
__global__ __launch_bounds__(256) void cvt_x_kernel(const float* __restrict__ in,
                                                    u16* __restrict__ out) {
  size_t t = (size_t)blockIdx.x * 256 + threadIdx.x;  // 8 elements per thread
  const float4* ip = (const float4*)in + t * 2;
  float4 a = ip[0], b = ip[1];
  uint4 o;
  o.x = f2bf(a.x) | ((u32)f2bf(a.y) << 16);
  o.y = f2bf(a.z) | ((u32)f2bf(a.w) << 16);
  o.z = f2bf(b.x) | ((u32)f2bf(b.y) << 16);
  o.w = f2bf(b.z) | ((u32)f2bf(b.w) << 16);
  *((uint4*)out + t) = o;
}

// ---------- per-expert transpose + convert: in [R][C] fp32 -> out [C][R] bf16 ----------
__global__ __launch_bounds__(256) void transpose_cvt(const float* __restrict__ in,
                                                     u16* __restrict__ out, int R, int C) {
  int e = blockIdx.z;
  const float* ip = in + (size_t)e * R * C;
  u16* op = out + (size_t)e * R * C;
  int r0 = blockIdx.y * 64, c0 = blockIdx.x * 64;
  __shared__ __align__(16) u16 t[64 * 72];  // stride 72 shorts = 144 B (16B mult)
  int tid = threadIdx.x;
  int i = tid >> 4;
  int j4 = (tid & 15) * 4;
  for (int p = 0; p < 4; ++p, i += 16) {
    float4 v = *(const float4*)(ip + (size_t)(r0 + i) * C + c0 + j4);
    t[(j4 + 0) * 72 + i] = f2bf(v.x);
    t[(j4 + 1) * 72 + i] = f2bf(v.y);
    t[(j4 + 2) * 72 + i] = f2bf(v.z);
    t[(j4 + 3) * 72 + i] = f2bf(v.w);
  }
  __syncthreads();
#pragma unroll
  for (int p = 0; p < 2; ++p) {
    int c = p * 256 + tid;
    int j = c >> 3, i0 = (c & 7) * 8;
    uint4 val = *(const uint4*)&t[j * 72 + i0];
    *(uint4*)(op + (size_t)(c0 + j) * R + r0 + i0) = val;
  }
}

// ---------- fc1: H[slot,f] = gelu(Xg @ W1 + b1), bf16 ----------
__global__ __launch_bounds__(256) void fc1_kernel(
    const u16* __restrict__ xb, const u16* __restrict__ w1t,
    const float* __restrict__ b1, const int* __restrict__ rowtok,
    const int* __restrict__ offsets, u16* __restrict__ H) {
  const int e = blockIdx.z;
  const int base = offsets[e];
  const int count = offsets[e + 1] - base;
  const int rt = blockIdx.y;
  if (rt * 128 >= count) return;
  const int ct = blockIdx.x;

  __shared__ __align__(16) __bf16 As[128 * 32];
  __shared__ __align__(16) __bf16 Bs[128 * 32];

  const int tid = threadIdx.x;
  const int lane = tid & 63;
  const int wave = tid >> 6;

  const int ra = tid >> 2;  // chunk row 0..63 (pass0); +64 pass1
  const int lastslot = base + count - 1;
  int s0 = base + rt * 128 + ra;       if (s0 > lastslot) s0 = lastslot;
  int s1 = base + rt * 128 + ra + 64;  if (s1 > lastslot) s1 = lastslot;
  const size_t koff = (size_t)(tid & 3) * 8;
  const u16* ga0 = xb + (size_t)rowtok[s0] * D_MODEL + koff;
  const u16* ga1 = xb + (size_t)rowtok[s1] * D_MODEL + koff;
  const u16* gb0 = w1t + (size_t)e * DIM_FF * D_MODEL + (size_t)(ct * 128 + ra) * D_MODEL + koff;
  const u16* gb1 = gb0 + (size_t)64 * D_MODEL;

  __bf16* lA0 = As + tid * 8;
  __bf16* lA1 = As + (tid + 256) * 8;
  __bf16* lB0 = Bs + tid * 8;
  __bf16* lB1 = Bs + (tid + 256) * 8;

  const int wm = (wave & 1) * 64;
  const int wn = (wave >> 1) * 64;
  const int quad = lane >> 4;
  const int lc = lane & 15;
  const __bf16* Ap = As + (wm + lc) * 32 + quad * 8;
  const __bf16* Bp = Bs + (wn + lc) * 32 + quad * 8;

  f32x4 acc[4][4];
#pragma unroll
  for (int i = 0; i < 4; ++i)
#pragma unroll
    for (int j = 0; j < 4; ++j) acc[i][j] = (f32x4)0.0f;

  for (int kt = 0; kt < D_MODEL / 32; ++kt) {
    gl2lds16(ga0 + kt * 32, lA0);
    gl2lds16(ga1 + kt * 32, lA1);
    gl2lds16(gb0 + kt * 32, lB0);
    gl2lds16(gb1 + kt * 32, lB1);
    __syncthreads();
    bf16x8 af[4], bfr[4];
#pragma unroll
    for (int mi = 0; mi < 4; ++mi) af[mi] = *(const bf16x8*)(Ap + mi * 16 * 32);
#pragma unroll
    for (int ni = 0; ni < 4; ++ni) bfr[ni] = *(const bf16x8*)(Bp + ni * 16 * 32);
#pragma unroll
    for (int mi = 0; mi < 4; ++mi)
#pragma unroll
      for (int ni = 0; ni < 4; ++ni)
        acc[mi][ni] = __builtin_amdgcn_mfma_f32_16x16x32_bf16(af[mi], bfr[ni], acc[mi][ni], 0, 0, 0);
    __syncthreads();
  }

  float bias[4];
#pragma unroll
  for (int ni = 0; ni < 4; ++ni) bias[ni] = b1[e * DIM_FF + ct * 128 + wn + ni * 16 + lc];
#pragma unroll
  for (int mi = 0; mi < 4; ++mi) {
#pragma unroll
    for (int r = 0; r < 4; ++r) {
      int m = wm + mi * 16 + quad * 4 + r;
      int grow = rt * 128 + m;
      if (grow < count) {
        size_t rowbase = (size_t)(base + grow) * DIM_FF + ct * 128 + wn;
#pragma unroll
        for (int ni = 0; ni < 4; ++ni) {
          float v = acc[mi][ni][r] + bias[ni];
          v = 0.5f * v * (1.0f + erff(v * 0.70710678118654752f));  // exact GELU
          H[rowbase + ni * 16 + lc] = f2bf(v);
        }
      }
    }
  }
}

// ---------- fc2: out[token] += wt * (H @ W2 + b2) ----------
__global__ __launch_bounds__(256) void fc2_kernel(
    const u16* __restrict__ H, const u16* __restrict__ w2t,
    const float* __restrict__ b2, const int* __restrict__ rowtok,
    const float* __restrict__ rowwt, const int* __restrict__ offsets,
    float* __restrict__ out) {
  const int e = blockIdx.z;
  const int base = offsets[e];
  const int count = offsets[e + 1] - base;
  const int rt = blockIdx.y;
  if (rt * 128 >= count) return;
  const int ct = blockIdx.x;  // 0..7 over D_MODEL

  __shared__ __align__(16) __bf16 As[128 * 32];
  __shared__ __align__(16) __bf16 Bs[128 * 32];

  const int tid = threadIdx.x;
  const int lane = tid & 63;
  const int wave = tid >> 6;

  const int ra = tid >> 2;
  const size_t koff = (size_t)(tid & 3) * 8;
  const u16* ga0 = H + (size_t)(base + rt * 128 + ra) * DIM_FF + koff;       // contiguous slots
  const u16* ga1 = ga0 + (size_t)64 * DIM_FF;
  const u16* gb0 = w2t + (size_t)e * D_MODEL * DIM_FF + (size_t)(ct * 128 + ra) * DIM_FF + koff;
  const u16* gb1 = gb0 + (size_t)64 * DIM_FF;

  __bf16* lA0 = As + tid * 8;
  __bf16* lA1 = As + (tid + 256) * 8;
  __bf16* lB0 = Bs + tid * 8;
  __bf16* lB1 = Bs + (tid + 256) * 8;

  const int wm = (wave & 1) * 64;
  const int wn = (wave >> 1) * 64;
  const int quad = lane >> 4;
  const int lc = lane & 15;
  const __bf16* Ap = As + (wm + lc) * 32 + quad * 8;
  const __bf16* Bp = Bs + (wn + lc) * 32 + quad * 8;

  f32x4 acc[4][4];
#pragma unroll
  for (int i = 0; i < 4; ++i)
#pragma unroll
    for (int j = 0; j < 4; ++j) acc[i][j] = (f32x4)0.0f;

  for (int kt = 0; kt < DIM_FF / 32; ++kt) {
    gl2lds16(ga0 + kt * 32, lA0);
    gl2lds16(ga1 + kt * 32, lA1);
    gl2lds16(gb0 + kt * 32, lB0);
    gl2lds16(gb1 + kt * 32, lB1);
    __syncthreads();
    bf16x8 af[4], bfr[4];
#pragma unroll
    for (int mi = 0; mi < 4; ++mi) af[mi] = *(const bf16x8*)(Ap + mi * 16 * 32);
#pragma unroll
    for (int ni = 0; ni < 4; ++ni) bfr[ni] = *(const bf16x8*)(Bp + ni * 16 * 32);
#pragma unroll
    for (int mi = 0; mi < 4; ++mi)
#pragma unroll
      for (int ni = 0; ni < 4; ++ni)
        acc[mi][ni] = __builtin_amdgcn_mfma_f32_16x16x32_bf16(af[mi], bfr[ni], acc[mi][ni], 0, 0, 0);
    __syncthreads();
  }

#pragma unroll
  for (int mi = 0; mi < 4; ++mi) {
#pragma unroll
    for (int r = 0; r < 4; ++r) {
      int m = wm + mi * 16 + quad * 4 + r;
      int grow = rt * 128 + m;
      if (grow < count) {
        int slot = base + grow;
        int tok = rowtok[slot];
        float wt = rowwt[slot];
        float* orow = out + (size_t)tok * D_MODEL + ct * 128 + wn;
#pragma unroll
        for (int ni = 0; ni < 4; ++ni) {
          float v = acc[mi][ni][r] + b2[e * D_MODEL + ct * 128 + wn + ni * 16 + lc];
          atomicAdd(orow + ni * 16 + lc, wt * v);
        }
      }
    }
  }
}

extern "C" void kernel_launch(void* const* d_in, const int* in_sizes, int n_in,
                              void* d_out, int out_size, void* d_ws, size_t ws_size,
                              hipStream_t stream) {
  (void)in_sizes; (void)n_in; (void)ws_size;
  const float* x  = (const float*)d_in[0];
  const float* Wg = (const float*)d_in[1];
  const float* bg = (const float*)d_in[2];
  const float* W1 = (const float*)d_in[3];
  const float* b1 = (const float*)d_in[4];
  const float* W2 = (const float*)d_in[5];
  const float* b2 = (const float*)d_in[6];
  float* out = (float*)d_out;

  char* ws = (char*)d_ws;
  int*   counts  = (int*)(ws + 0);
  int*   fill    = (int*)(ws + 64);
  int*   offsets = (int*)(ws + 128);
  int*   eidx    = (int*)(ws + 4096);
  float* ew      = (float*)(ws + 4096 + 65536);
  int*   rowtok  = (int*)(ws + 4096 + 2 * 65536);
  float* rowwt   = (float*)(ws + 4096 + 3 * 65536);
  u16*   xb      = (u16*)(ws + 4096 + 4 * 65536);
  u16*   w1t     = xb + (size_t)N_TOKENS * D_MODEL;
  u16*   w2t     = w1t;  // ALIASED: W2 transposed after fc1 finishes (saves 64MB ws)
  u16*   H       = w1t + (size_t)N_EXPERTS * DIM_FF * D_MODEL;
  // H capacity: MAX_SLOTS + 128 pad rows; total ws use ~222 MB

  hipMemsetAsync(ws, 0, 4096, stream);
  hipMemsetAsync(d_out, 0, (size_t)out_size * sizeof(float), stream);

  gate_kernel<<<N_TOKENS / 4, 256, 0, stream>>>(x, Wg, bg, eidx, ew, counts);
  scan_kernel<<<1, 64, 0, stream>>>(counts, offsets);
  fill_kernel<<<N_TOKENS / 256, 256, 0, stream>>>(eidx, ew, offsets, fill, rowtok, rowwt);
  cvt_x_kernel<<<(N_TOKENS * D_MODEL / 8) / 256, 256, 0, stream>>>(x, xb);
  transpose_cvt<<<dim3(DIM_FF / 64, D_MODEL / 64, N_EXPERTS), 256, 0, stream>>>(W1, w1t, D_MODEL, DIM_FF);
  fc1_kernel<<<dim3(DIM_FF / 128, 64, N_EXPERTS), 256, 0, stream>>>(xb, w1t, b1, rowtok, offsets, H);
  transpose_cvt<<<dim3(D_MODEL / 64, DIM_FF / 64, N_EXPERTS), 256, 0, stream>>>(W2, w2t, DIM_FF, D_MODEL);
  fc2_kernel<<<dim3(D_MODEL / 128, 64, N_EXPERTS), 256, 0, stream>>>(H, w2t, b2, rowtok, rowwt, offsets, out);
}

// Round 2
// 1036.281 us; speedup vs baseline: 1.0661x; 1.0661x over previous
//
#include <hip/hip_runtime.h>
#include <cstdint>

typedef unsigned short u16;
typedef unsigned int u32;

#define N_TOKENS 8192
#define D_MODEL 1024
#define DIM_FF 4096
#define N_EXPERTS 8
#define MAX_SLOTS (N_TOKENS * 2)

typedef __bf16 bf16x8 __attribute__((ext_vector_type(8)));
typedef float f32x4 __attribute__((ext_vector_type(4)));

// ---------- helpers ----------
__device__ __forceinline__ u16 f2bf(float f) {
  u32 u = __float_as_uint(f);
  u32 r = (u + 0x7FFFu + ((u >> 16) & 1u)) >> 16;  // RNE
  return (u16)r;
}

// async global->LDS, 16B per lane; LDS dst = wave-uniform base + lane*16
__device__ __forceinline__ void gl2lds16(const void* g, void* l) {
  __builtin_amdgcn_global_load_lds(
      (__attribute__((address_space(1))) void*)(g),
      (__attribute__((address_space(3))) void*)(l), 16, 0, 0);
}

// ---------- gate: logits -> softmax -> top2 -> renorm ----------
__global__ __launch_bounds__(256) void gate_kernel(
    const float* __restrict__ x, const float* __restrict__ Wg,
    const float* __restrict__ bg, int* __restrict__ eidx,
    float* __restrict__ ew, int* __restrict__ counts) {
  int tok = (int)((blockIdx.x * 256 + threadIdx.x) >> 6);
  int lane = threadIdx.x & 63;
  const float* xr = x + (size_t)tok * D_MODEL;
  float acc[8] = {0.f, 0.f, 0.f, 0.f, 0.f, 0.f, 0.f, 0.f};
  for (int j = 0; j < 16; ++j) {
    int d = lane + 64 * j;
    float xv = xr[d];
    float4 wa = *(const float4*)(Wg + d * 8);
    float4 wb = *(const float4*)(Wg + d * 8 + 4);
    acc[0] += xv * wa.x; acc[1] += xv * wa.y; acc[2] += xv * wa.z; acc[3] += xv * wa.w;
    acc[4] += xv * wb.x; acc[5] += xv * wb.y; acc[6] += xv * wb.z; acc[7] += xv * wb.w;
  }
#pragma unroll
  for (int off = 32; off > 0; off >>= 1) {
#pragma unroll
    for (int e = 0; e < 8; ++e) acc[e] += __shfl_xor(acc[e], off, 64);
  }
  if (lane == 0) {
    float p[8], m = -1e30f;
#pragma unroll
    for (int e = 0; e < 8; ++e) { p[e] = acc[e] + bg[e]; m = fmaxf(m, p[e]); }
    float s = 0.f;
#pragma unroll
    for (int e = 0; e < 8; ++e) { p[e] = __expf(p[e] - m); s += p[e]; }
#pragma unroll
    for (int e = 0; e < 8; ++e) p[e] /= s;
    int i0 = 0;
#pragma unroll
    for (int e = 1; e < 8; ++e) if (p[e] > p[i0]) i0 = e;
    int i1 = (i0 == 0) ? 1 : 0;
#pragma unroll
    for (int e = 0; e < 8; ++e) if (e != i0 && p[e] > p[i1]) i1 = e;
    float denom = p[i0] + p[i1] + 1e-9f;
    eidx[2 * tok] = i0; eidx[2 * tok + 1] = i1;
    ew[2 * tok] = p[i0] / denom; ew[2 * tok + 1] = p[i1] / denom;
    atomicAdd(&counts[i0], 1);
    atomicAdd(&counts[i1], 1);
  }
}

__global__ void scan_kernel(const int* __restrict__ counts, int* __restrict__ offsets) {
  if (threadIdx.x == 0) {
    int o = 0;
    for (int e = 0; e < N_EXPERTS; ++e) { offsets[e] = o; o += counts[e]; }
    offsets[N_EXPERTS] = o;
  }
}

__global__ __launch_bounds__(256) void fill_kernel(
    const int* __restrict__ eidx, const float* __restrict__ ew,
    const int* __restrict__ offsets, int* __restrict__ fill,
    int* __restrict__ rowtok, float* __restrict__ rowwt,
    int* __restrict__ tokslot) {
  int t = blockIdx.x * 256 + threadIdx.x;
#pragma unroll
  for (int k = 0; k < 2; ++k) {
    int e = eidx[2 * t + k];
    int pos = offsets[e] + atomicAdd(&fill[e], 1);
    rowtok[pos] = t;
    rowwt[pos] = ew[2 * t + k];
    tokslot[2 * t + k] = pos;
  }
}

// ---------- fp32 -> bf16 copy of x ----------
__global__ __launch_bounds__(256) void cvt_x_kernel(const float* __restrict__ in,
                                                    u16* __restrict__ out) {
  size_t t = (size_t)blockIdx.x * 256 + threadIdx.x;  // 8 elements per thread
  const float4* ip = (const float4*)in + t * 2;
  float4 a = ip[0], b = ip[1];
  uint4 o;
  o.x = f2bf(a.x) | ((u32)f2bf(a.y) << 16);
  o.y = f2bf(a.z) | ((u32)f2bf(a.w) << 16);
  o.z = f2bf(b.x) | ((u32)f2bf(b.y) << 16);
  o.w = f2bf(b.z) | ((u32)f2bf(b.w) << 16);
  *((uint4*)out + t) = o;
}

// ---------- per-expert transpose + convert: in [R][C] fp32 -> out [C][R] bf16 ----------
__global__ __launch_bounds__(256) void transpose_cvt(const float* __restrict__ in,
                                                     u16* __restrict__ out, int R, int C) {
  int e = blockIdx.z;
  const float* ip = in + (size_t)e * R * C;
  u16* op = out + (size_t)e * R * C;
  int r0 = blockIdx.y * 64, c0 = blockIdx.x * 64;
  __shared__ __align__(16) u16 t[64 * 72];  // stride 72 shorts = 144 B (16B mult)
  int tid = threadIdx.x;
  int i = tid >> 4;
  int j4 = (tid & 15) * 4;
  for (int p = 0; p < 4; ++p, i += 16) {
    float4 v = *(const float4*)(ip + (size_t)(r0 + i) * C + c0 + j4);
    t[(j4 + 0) * 72 + i] = f2bf(v.x);
    t[(j4 + 1) * 72 + i] = f2bf(v.y);
    t[(j4 + 2) * 72 + i] = f2bf(v.z);
    t[(j4 + 3) * 72 + i] = f2bf(v.w);
  }
  __syncthreads();
#pragma unroll
  for (int p = 0; p < 2; ++p) {
    int c = p * 256 + tid;
    int j = c >> 3, i0 = (c & 7) * 8;
    uint4 val = *(const uint4*)&t[j * 72 + i0];
    *(uint4*)(op + (size_t)(c0 + j) * R + r0 + i0) = val;
  }
}

// ---------- fc1: H[slot,f] = gelu(Xg @ W1 + b1), bf16 ----------
// 1-D grid, XCD swizzle: expert = b&7 (pins expert to XCD), rt-fast within expert.
__global__ __launch_bounds__(256) void fc1_kernel(
    const u16* __restrict__ xb, const u16* __restrict__ w1t,
    const float* __restrict__ b1, const int* __restrict__ rowtok,
    const int* __restrict__ offsets, u16* __restrict__ H) {
  const int b = blockIdx.x;
  const int e = b & 7;
  const int lin = b >> 3;      // 0..2047
  const int rt = lin & 63;     // rt-fast: consecutive active blocks share B col
  const int ct = lin >> 6;     // 0..31
  const int base = offsets[e];
  const int count = offsets[e + 1] - base;
  if (rt * 128 >= count) return;

  __shared__ __align__(16) __bf16 As[128 * 32];
  __shared__ __align__(16) __bf16 Bs[128 * 32];

  const int tid = threadIdx.x;
  const int lane = tid & 63;
  const int wave = tid >> 6;

  const int ra = tid >> 2;  // chunk row 0..63 (pass0); +64 pass1
  const int lastslot = base + count - 1;
  int s0 = base + rt * 128 + ra;       if (s0 > lastslot) s0 = lastslot;
  int s1 = base + rt * 128 + ra + 64;  if (s1 > lastslot) s1 = lastslot;
  const size_t koff = (size_t)(tid & 3) * 8;
  const u16* ga0 = xb + (size_t)rowtok[s0] * D_MODEL + koff;
  const u16* ga1 = xb + (size_t)rowtok[s1] * D_MODEL + koff;
  const u16* gb0 = w1t + (size_t)e * DIM_FF * D_MODEL + (size_t)(ct * 128 + ra) * D_MODEL + koff;
  const u16* gb1 = gb0 + (size_t)64 * D_MODEL;

  __bf16* lA0 = As + tid * 8;
  __bf16* lA1 = As + (tid + 256) * 8;
  __bf16* lB0 = Bs + tid * 8;
  __bf16* lB1 = Bs + (tid + 256) * 8;

  const int wm = (wave & 1) * 64;
  const int wn = (wave >> 1) * 64;
  const int quad = lane >> 4;
  const int lc = lane & 15;
  const __bf16* Ap = As + (wm + lc) * 32 + quad * 8;
  const __bf16* Bp = Bs + (wn + lc) * 32 + quad * 8;

  f32x4 acc[4][4];
#pragma unroll
  for (int i = 0; i < 4; ++i)
#pragma unroll
    for (int j = 0; j < 4; ++j) acc[i][j] = (f32x4)0.0f;

  for (int kt = 0; kt < D_MODEL / 32; ++kt) {
    gl2lds16(ga0 + kt * 32, lA0);
    gl2lds16(ga1 + kt * 32, lA1);
    gl2lds16(gb0 + kt * 32, lB0);
    gl2lds16(gb1 + kt * 32, lB1);
    __syncthreads();
    bf16x8 af[4], bfr[4];
#pragma unroll
    for (int mi = 0; mi < 4; ++mi) af[mi] = *(const bf16x8*)(Ap + mi * 16 * 32);
#pragma unroll
    for (int ni = 0; ni < 4; ++ni) bfr[ni] = *(const bf16x8*)(Bp + ni * 16 * 32);
#pragma unroll
    for (int mi = 0; mi < 4; ++mi)
#pragma unroll
      for (int ni = 0; ni < 4; ++ni)
        acc[mi][ni] = __builtin_amdgcn_mfma_f32_16x16x32_bf16(af[mi], bfr[ni], acc[mi][ni], 0, 0, 0);
    __syncthreads();
  }

  float bias[4];
#pragma unroll
  for (int ni = 0; ni < 4; ++ni) bias[ni] = b1[e * DIM_FF + ct * 128 + wn + ni * 16 + lc];
#pragma unroll
  for (int mi = 0; mi < 4; ++mi) {
#pragma unroll
    for (int r = 0; r < 4; ++r) {
      int m = wm + mi * 16 + quad * 4 + r;
      int grow = rt * 128 + m;
      if (grow < count) {
        size_t rowbase = (size_t)(base + grow) * DIM_FF + ct * 128 + wn;
#pragma unroll
        for (int ni = 0; ni < 4; ++ni) {
          float v = acc[mi][ni][r] + bias[ni];
          v = 0.5f * v * (1.0f + erff(v * 0.70710678118654752f));  // exact GELU
          H[rowbase + ni * 16 + lc] = f2bf(v);
        }
      }
    }
  }
}

// ---------- fc2: y[slot] = H @ W2 + b2 (plain stores), or atomic fallback ----------
__global__ __launch_bounds__(256) void fc2_kernel(
    const u16* __restrict__ H, const u16* __restrict__ w2t,
    const float* __restrict__ b2, const int* __restrict__ rowtok,
    const float* __restrict__ rowwt, const int* __restrict__ offsets,
    float* __restrict__ y, float* __restrict__ out, int use_y) {
  const int b = blockIdx.x;
  const int e = b & 7;
  const int lin = b >> 3;      // 0..511
  const int rt = lin & 63;
  const int ct = lin >> 6;     // 0..7
  const int base = offsets[e];
  const int count = offsets[e + 1] - base;
  if (rt * 128 >= count) return;

  __shared__ __align__(16) __bf16 As[128 * 32];
  __shared__ __align__(16) __bf16 Bs[128 * 32];

  const int tid = threadIdx.x;
  const int lane = tid & 63;
  const int wave = tid >> 6;

  const int ra = tid >> 2;
  const size_t koff = (size_t)(tid & 3) * 8;
  const u16* ga0 = H + (size_t)(base + rt * 128 + ra) * DIM_FF + koff;  // contiguous slots
  const u16* ga1 = ga0 + (size_t)64 * DIM_FF;
  const u16* gb0 = w2t + (size_t)e * D_MODEL * DIM_FF + (size_t)(ct * 128 + ra) * DIM_FF + koff;
  const u16* gb1 = gb0 + (size_t)64 * DIM_FF;

  __bf16* lA0 = As + tid * 8;
  __bf16* lA1 = As + (tid + 256) * 8;
  __bf16* lB0 = Bs + tid * 8;
  __bf16* lB1 = Bs + (tid + 256) * 8;

  const int wm = (wave & 1) * 64;
  const int wn = (wave >> 1) * 64;
  const int quad = lane >> 4;
  const int lc = lane & 15;
  const __bf16* Ap = As + (wm + lc) * 32 + quad * 8;
  const __bf16* Bp = Bs + (wn + lc) * 32 + quad * 8;

  f32x4 acc[4][4];
#pragma unroll
  for (int i = 0; i < 4; ++i)
#pragma unroll
    for (int j = 0; j < 4; ++j) acc[i][j] = (f32x4)0.0f;

  for (int kt = 0; kt < DIM_FF / 32; ++kt) {
    gl2lds16(ga0 + kt * 32, lA0);
    gl2lds16(ga1 + kt * 32, lA1);
    gl2lds16(gb0 + kt * 32, lB0);
    gl2lds16(gb1 + kt * 32, lB1);
    __syncthreads();
    bf16x8 af[4], bfr[4];
#pragma unroll
    for (int mi = 0; mi < 4; ++mi) af[mi] = *(const bf16x8*)(Ap + mi * 16 * 32);
#pragma unroll
    for (int ni = 0; ni < 4; ++ni) bfr[ni] = *(const bf16x8*)(Bp + ni * 16 * 32);
#pragma unroll
    for (int mi = 0; mi < 4; ++mi)
#pragma unroll
      for (int ni = 0; ni < 4; ++ni)
        acc[mi][ni] = __builtin_amdgcn_mfma_f32_16x16x32_bf16(af[mi], bfr[ni], acc[mi][ni], 0, 0, 0);
    __syncthreads();
  }

  float bias[4];
#pragma unroll
  for (int ni = 0; ni < 4; ++ni) bias[ni] = b2[e * D_MODEL + ct * 128 + wn + ni * 16 + lc];

  if (use_y) {
#pragma unroll
    for (int mi = 0; mi < 4; ++mi) {
#pragma unroll
      for (int r = 0; r < 4; ++r) {
        int m = wm + mi * 16 + quad * 4 + r;
        int grow = rt * 128 + m;
        if (grow < count) {
          float* yrow = y + (size_t)(base + grow) * D_MODEL + ct * 128 + wn;
#pragma unroll
          for (int ni = 0; ni < 4; ++ni) yrow[ni * 16 + lc] = acc[mi][ni][r] + bias[ni];
        }
      }
    }
  } else {
#pragma unroll
    for (int mi = 0; mi < 4; ++mi) {
#pragma unroll
      for (int r = 0; r < 4; ++r) {
        int m = wm + mi * 16 + quad * 4 + r;
        int grow = rt * 128 + m;
        if (grow < count) {
          int slot = base + grow;
          float wt = rowwt[slot];
          float* orow = out + (size_t)rowtok[slot] * D_MODEL + ct * 128 + wn;
#pragma unroll
          for (int ni = 0; ni < 4; ++ni)
            atomicAdd(orow + ni * 16 + lc, wt * (acc[mi][ni][r] + bias[ni]));
        }
      }
    }
  }
}

// ---------- combine: out[t] = w0*y[s0] + w1*y[s1] ----------
__global__ __launch_bounds__(256) void combine_kernel(
    const float* __restrict__ y, const int* __restrict__ tokslot,
    const float* __restrict__ ew, float* __restrict__ out) {
  int gid = blockIdx.x * 256 + threadIdx.x;  // one float4 per thread
  int t = gid >> 8;
  int c = (gid & 255) * 4;
  int s0 = tokslot[2 * t], s1 = tokslot[2 * t + 1];
  float w0 = ew[2 * t], w1 = ew[2 * t + 1];
  float4 a = *(const float4*)(y + (size_t)s0 * D_MODEL + c);
  float4 bb = *(const float4*)(y + (size_t)s1 * D_MODEL + c);
  float4 o;
  o.x = w0 * a.x + w1 * bb.x;
  o.y = w0 * a.y + w1 * bb.y;
  o.z = w0 * a.z + w1 * bb.z;
  o.w = w0 * a.w + w1 * bb.w;
  *(float4*)(out + (size_t)t * D_MODEL + c) = o;
}

extern "C" void kernel_launch(void* const* d_in, const int* in_sizes, int n_in,
                              void* d_out, int out_size, void* d_ws, size_t ws_size,
                              hipStream_t stream) {
  (void)in_sizes; (void)n_in;
  const float* x  = (const float*)d_in[0];
  const float* Wg = (const float*)d_in[1];
  const float* bg = (const float*)d_in[2];
  const float* W1 = (const float*)d_in[3];
  const float* b1 = (const float*)d_in[4];
  const float* W2 = (const float*)d_in[5];
  const float* b2 = (const float*)d_in[6];
  float* out = (float*)d_out;

  char* ws = (char*)d_ws;
  size_t off = 0;
  int*   counts  = (int*)(ws + 0);
  int*   fill    = (int*)(ws + 64);
  int*   offsets = (int*)(ws + 128);
  off = 4096;
  int*   eidx    = (int*)(ws + off); off += 65536;
  float* ew      = (float*)(ws + off); off += 65536;
  int*   rowtok  = (int*)(ws + off); off += 65536;
  float* rowwt   = (float*)(ws + off); off += 65536;
  int*   tokslot = (int*)(ws + off); off += 65536;
  u16*   xb      = (u16*)(ws + off); off += (size_t)N_TOKENS * D_MODEL * 2;
  u16*   w1t     = (u16*)(ws + off);
  u16*   w2t     = w1t;  // ALIASED: W2 transposed after fc1 finishes reading w1t
  off += (size_t)N_EXPERTS * DIM_FF * D_MODEL * 2;
  u16*   H       = (u16*)(ws + off);
  off += (size_t)(MAX_SLOTS + 128) * DIM_FF * 2;  // +128 rows: unguarded tile reads
  float* y       = (float*)(ws + off);
  size_t need_y  = off + (size_t)MAX_SLOTS * D_MODEL * 4;
  const int use_y = (ws_size >= need_y) ? 1 : 0;

  hipMemsetAsync(ws, 0, 4096, stream);
  if (!use_y) hipMemsetAsync(d_out, 0, (size_t)out_size * sizeof(float), stream);

  gate_kernel<<<N_TOKENS / 4, 256, 0, stream>>>(x, Wg, bg, eidx, ew, counts);
  scan_kernel<<<1, 64, 0, stream>>>(counts, offsets);
  fill_kernel<<<N_TOKENS / 256, 256, 0, stream>>>(eidx, ew, offsets, fill, rowtok, rowwt, tokslot);
  cvt_x_kernel<<<(N_TOKENS * D_MODEL / 8) / 256, 256, 0, stream>>>(x, xb);
  transpose_cvt<<<dim3(DIM_FF / 64, D_MODEL / 64, N_EXPERTS), 256, 0, stream>>>(W1, w1t, D_MODEL, DIM_FF);
  fc1_kernel<<<N_EXPERTS * (DIM_FF / 128) * 64, 256, 0, stream>>>(xb, w1t, b1, rowtok, offsets, H);
  transpose_cvt<<<dim3(D_MODEL / 64, DIM_FF / 64, N_EXPERTS), 256, 0, stream>>>(W2, w2t, DIM_FF, D_MODEL);
  fc2_kernel<<<N_EXPERTS * (D_MODEL / 128) * 64, 256, 0, stream>>>(H, w2t, b2, rowtok, rowwt, offsets, y, out, use_y);
  if (use_y)
    combine_kernel<<<(N_TOKENS * D_MODEL / 4) / 256, 256, 0, stream>>>(y, tokslot, ew, out);
}

// Round 3
// 782.443 us; speedup vs baseline: 1.4120x; 1.3244x over previous
//
#include <hip/hip_runtime.h>
#include <cstdint>

typedef unsigned short u16;
typedef unsigned int u32;

#define N_TOKENS 8192
#define D_MODEL 1024
#define DIM_FF 4096
#define N_EXPERTS 8
#define MAX_SLOTS (N_TOKENS * 2)

typedef __bf16 bf16x8 __attribute__((ext_vector_type(8)));
typedef float f32x4 __attribute__((ext_vector_type(4)));

// ---------- helpers ----------
__device__ __forceinline__ u16 f2bf(float f) {
  u32 u = __float_as_uint(f);
  u32 r = (u + 0x7FFFu + ((u >> 16) & 1u)) >> 16;  // RNE
  return (u16)r;
}

// async global->LDS, 16B per lane; LDS dst = wave-uniform base + lane*16
__device__ __forceinline__ void gl2lds16(const void* g, void* l) {
  __builtin_amdgcn_global_load_lds(
      (__attribute__((address_space(1))) void*)(g),
      (__attribute__((address_space(3))) void*)(l), 16, 0, 0);
}

// ---------- gate: logits -> softmax -> top2 -> renorm (NO atomics) ----------
__global__ __launch_bounds__(256) void gate_kernel(
    const float* __restrict__ x, const float* __restrict__ Wg,
    const float* __restrict__ bg, int* __restrict__ eidx,
    float* __restrict__ ew) {
  int tok = (int)((blockIdx.x * 256 + threadIdx.x) >> 6);
  int lane = threadIdx.x & 63;
  const float* xr = x + (size_t)tok * D_MODEL;
  float acc[8] = {0.f, 0.f, 0.f, 0.f, 0.f, 0.f, 0.f, 0.f};
  for (int j = 0; j < 16; ++j) {
    int d = lane + 64 * j;
    float xv = xr[d];
    float4 wa = *(const float4*)(Wg + d * 8);
    float4 wb = *(const float4*)(Wg + d * 8 + 4);
    acc[0] += xv * wa.x; acc[1] += xv * wa.y; acc[2] += xv * wa.z; acc[3] += xv * wa.w;
    acc[4] += xv * wb.x; acc[5] += xv * wb.y; acc[6] += xv * wb.z; acc[7] += xv * wb.w;
  }
#pragma unroll
  for (int off = 32; off > 0; off >>= 1) {
#pragma unroll
    for (int e = 0; e < 8; ++e) acc[e] += __shfl_xor(acc[e], off, 64);
  }
  if (lane == 0) {
    float p[8], m = -1e30f;
#pragma unroll
    for (int e = 0; e < 8; ++e) { p[e] = acc[e] + bg[e]; m = fmaxf(m, p[e]); }
    float s = 0.f;
#pragma unroll
    for (int e = 0; e < 8; ++e) { p[e] = __expf(p[e] - m); s += p[e]; }
#pragma unroll
    for (int e = 0; e < 8; ++e) p[e] /= s;
    int i0 = 0;
#pragma unroll
    for (int e = 1; e < 8; ++e) if (p[e] > p[i0]) i0 = e;
    int i1 = (i0 == 0) ? 1 : 0;
#pragma unroll
    for (int e = 0; e < 8; ++e) if (e != i0 && p[e] > p[i1]) i1 = e;
    float denom = p[i0] + p[i1] + 1e-9f;
    eidx[2 * tok] = i0; eidx[2 * tok + 1] = i1;
    ew[2 * tok] = p[i0] / denom; ew[2 * tok + 1] = p[i1] / denom;
  }
}

// ---------- count: per-block LDS histogram -> 8 global atomics/block ----------
__global__ __launch_bounds__(256) void count_kernel(const int* __restrict__ eidx,
                                                    int* __restrict__ counts) {
  __shared__ int lc[N_EXPERTS];
  int tid = threadIdx.x;
  if (tid < N_EXPERTS) lc[tid] = 0;
  __syncthreads();
  int t = blockIdx.x * 256 + tid;
  atomicAdd(&lc[eidx[2 * t]], 1);
  atomicAdd(&lc[eidx[2 * t + 1]], 1);
  __syncthreads();
  if (tid < N_EXPERTS) atomicAdd(&counts[tid], lc[tid]);
}

__global__ void scan_kernel(const int* __restrict__ counts, int* __restrict__ offsets) {
  if (threadIdx.x == 0) {
    int o = 0;
    for (int e = 0; e < N_EXPERTS; ++e) { offsets[e] = o; o += counts[e]; }
    offsets[N_EXPERTS] = o;
  }
}

// ---------- fill: block-aggregated range claiming ----------
__global__ __launch_bounds__(256) void fill_kernel(
    const int* __restrict__ eidx, const float* __restrict__ ew,
    const int* __restrict__ offsets, int* __restrict__ fill,
    int* __restrict__ rowtok, float* __restrict__ rowwt,
    int* __restrict__ tokslot) {
  __shared__ int lc[N_EXPERTS];
  __shared__ int lbase[N_EXPERTS];
  int tid = threadIdx.x;
  if (tid < N_EXPERTS) lc[tid] = 0;
  __syncthreads();
  int t = blockIdx.x * 256 + tid;
  int e0 = eidx[2 * t], e1 = eidx[2 * t + 1];
  int p0 = atomicAdd(&lc[e0], 1);
  int p1 = atomicAdd(&lc[e1], 1);
  __syncthreads();
  if (tid < N_EXPERTS) lbase[tid] = atomicAdd(&fill[tid], lc[tid]);
  __syncthreads();
  int pos0 = offsets[e0] + lbase[e0] + p0;
  int pos1 = offsets[e1] + lbase[e1] + p1;
  rowtok[pos0] = t; rowwt[pos0] = ew[2 * t];     tokslot[2 * t] = pos0;
  rowtok[pos1] = t; rowwt[pos1] = ew[2 * t + 1]; tokslot[2 * t + 1] = pos1;
}

// ---------- fp32 -> bf16 copy of x ----------
__global__ __launch_bounds__(256) void cvt_x_kernel(const float* __restrict__ in,
                                                    u16* __restrict__ out) {
  size_t t = (size_t)blockIdx.x * 256 + threadIdx.x;  // 8 elements per thread
  const float4* ip = (const float4*)in + t * 2;
  float4 a = ip[0], b = ip[1];
  uint4 o;
  o.x = f2bf(a.x) | ((u32)f2bf(a.y) << 16);
  o.y = f2bf(a.z) | ((u32)f2bf(a.w) << 16);
  o.z = f2bf(b.x) | ((u32)f2bf(b.y) << 16);
  o.w = f2bf(b.z) | ((u32)f2bf(b.w) << 16);
  *((uint4*)out + t) = o;
}

// ---------- per-expert transpose + convert: in [R][C] fp32 -> out [C][R] bf16 ----------
__global__ __launch_bounds__(256) void transpose_cvt(const float* __restrict__ in,
                                                     u16* __restrict__ out, int R, int C) {
  int e = blockIdx.z;
  const float* ip = in + (size_t)e * R * C;
  u16* op = out + (size_t)e * R * C;
  int r0 = blockIdx.y * 64, c0 = blockIdx.x * 64;
  __shared__ __align__(16) u16 t[64 * 72];  // stride 72 shorts = 144 B (16B mult)
  int tid = threadIdx.x;
  int i = tid >> 4;
  int j4 = (tid & 15) * 4;
  for (int p = 0; p < 4; ++p, i += 16) {
    float4 v = *(const float4*)(ip + (size_t)(r0 + i) * C + c0 + j4);
    t[(j4 + 0) * 72 + i] = f2bf(v.x);
    t[(j4 + 1) * 72 + i] = f2bf(v.y);
    t[(j4 + 2) * 72 + i] = f2bf(v.z);
    t[(j4 + 3) * 72 + i] = f2bf(v.w);
  }
  __syncthreads();
#pragma unroll
  for (int p = 0; p < 2; ++p) {
    int c = p * 256 + tid;
    int j = c >> 3, i0 = (c & 7) * 8;
    uint4 val = *(const uint4*)&t[j * 72 + i0];
    *(uint4*)(op + (size_t)(c0 + j) * R + r0 + i0) = val;
  }
}

// ---------- fc1: H[slot,f] = gelu(Xg @ W1 + b1), bf16 ----------
// 1-D grid, XCD swizzle: expert = b&7 (pins expert to XCD), rt-fast within expert.
__global__ __launch_bounds__(256) void fc1_kernel(
    const u16* __restrict__ xb, const u16* __restrict__ w1t,
    const float* __restrict__ b1, const int* __restrict__ rowtok,
    const int* __restrict__ offsets, u16* __restrict__ H) {
  const int b = blockIdx.x;
  const int e = b & 7;
  const int lin = b >> 3;      // 0..2047
  const int rt = lin & 63;     // rt-fast: consecutive active blocks share B col
  const int ct = lin >> 6;     // 0..31
  const int base = offsets[e];
  const int count = offsets[e + 1] - base;
  if (rt * 128 >= count) return;

  __shared__ __align__(16) __bf16 As[128 * 32];
  __shared__ __align__(16) __bf16 Bs[128 * 32];

  const int tid = threadIdx.x;
  const int lane = tid & 63;
  const int wave = tid >> 6;

  const int ra = tid >> 2;  // chunk row 0..63 (pass0); +64 pass1
  const int lastslot = base + count - 1;
  int s0 = base + rt * 128 + ra;       if (s0 > lastslot) s0 = lastslot;
  int s1 = base + rt * 128 + ra + 64;  if (s1 > lastslot) s1 = lastslot;
  const size_t koff = (size_t)(tid & 3) * 8;
  const u16* ga0 = xb + (size_t)rowtok[s0] * D_MODEL + koff;
  const u16* ga1 = xb + (size_t)rowtok[s1] * D_MODEL + koff;
  const u16* gb0 = w1t + (size_t)e * DIM_FF * D_MODEL + (size_t)(ct * 128 + ra) * D_MODEL + koff;
  const u16* gb1 = gb0 + (size_t)64 * D_MODEL;

  __bf16* lA0 = As + tid * 8;
  __bf16* lA1 = As + (tid + 256) * 8;
  __bf16* lB0 = Bs + tid * 8;
  __bf16* lB1 = Bs + (tid + 256) * 8;

  const int wm = (wave & 1) * 64;
  const int wn = (wave >> 1) * 64;
  const int quad = lane >> 4;
  const int lc = lane & 15;
  const __bf16* Ap = As + (wm + lc) * 32 + quad * 8;
  const __bf16* Bp = Bs + (wn + lc) * 32 + quad * 8;

  f32x4 acc[4][4];
#pragma unroll
  for (int i = 0; i < 4; ++i)
#pragma unroll
    for (int j = 0; j < 4; ++j) acc[i][j] = (f32x4)0.0f;

  for (int kt = 0; kt < D_MODEL / 32; ++kt) {
    gl2lds16(ga0 + kt * 32, lA0);
    gl2lds16(ga1 + kt * 32, lA1);
    gl2lds16(gb0 + kt * 32, lB0);
    gl2lds16(gb1 + kt * 32, lB1);
    __syncthreads();
    bf16x8 af[4], bfr[4];
#pragma unroll
    for (int mi = 0; mi < 4; ++mi) af[mi] = *(const bf16x8*)(Ap + mi * 16 * 32);
#pragma unroll
    for (int ni = 0; ni < 4; ++ni) bfr[ni] = *(const bf16x8*)(Bp + ni * 16 * 32);
#pragma unroll
    for (int mi = 0; mi < 4; ++mi)
#pragma unroll
      for (int ni = 0; ni < 4; ++ni)
        acc[mi][ni] = __builtin_amdgcn_mfma_f32_16x16x32_bf16(af[mi], bfr[ni], acc[mi][ni], 0, 0, 0);
    __syncthreads();
  }

  float bias[4];
#pragma unroll
  for (int ni = 0; ni < 4; ++ni) bias[ni] = b1[e * DIM_FF + ct * 128 + wn + ni * 16 + lc];
#pragma unroll
  for (int mi = 0; mi < 4; ++mi) {
#pragma unroll
    for (int r = 0; r < 4; ++r) {
      int m = wm + mi * 16 + quad * 4 + r;
      int grow = rt * 128 + m;
      if (grow < count) {
        size_t rowbase = (size_t)(base + grow) * DIM_FF + ct * 128 + wn;
#pragma unroll
        for (int ni = 0; ni < 4; ++ni) {
          float v = acc[mi][ni][r] + bias[ni];
          // tanh-form GELU: gelu(v) = v*u/(u+1), u = exp2(2.302208*(v+0.044715 v^3))
          // max abs err vs exact GELU ~3e-4, << bf16 rounding of H
          float t3 = v * (1.0f + 0.044715f * v * v);
          float u = __builtin_amdgcn_exp2f(fminf(2.302208f * t3, 80.0f));
          float h = v * u * __builtin_amdgcn_rcpf(u + 1.0f);
          H[rowbase + ni * 16 + lc] = f2bf(h);
        }
      }
    }
  }
}

// ---------- fc2: y[slot] = H @ W2 + b2 (plain stores), or atomic fallback ----------
__global__ __launch_bounds__(256) void fc2_kernel(
    const u16* __restrict__ H, const u16* __restrict__ w2t,
    const float* __restrict__ b2, const int* __restrict__ rowtok,
    const float* __restrict__ rowwt, const int* __restrict__ offsets,
    float* __restrict__ y, float* __restrict__ out, int use_y) {
  const int b = blockIdx.x;
  const int e = b & 7;
  const int lin = b >> 3;      // 0..511
  const int rt = lin & 63;
  const int ct = lin >> 6;     // 0..7
  const int base = offsets[e];
  const int count = offsets[e + 1] - base;
  if (rt * 128 >= count) return;

  __shared__ __align__(16) __bf16 As[128 * 32];
  __shared__ __align__(16) __bf16 Bs[128 * 32];

  const int tid = threadIdx.x;
  const int lane = tid & 63;
  const int wave = tid >> 6;

  const int ra = tid >> 2;
  const size_t koff = (size_t)(tid & 3) * 8;
  const u16* ga0 = H + (size_t)(base + rt * 128 + ra) * DIM_FF + koff;  // contiguous slots
  const u16* ga1 = ga0 + (size_t)64 * DIM_FF;
  const u16* gb0 = w2t + (size_t)e * D_MODEL * DIM_FF + (size_t)(ct * 128 + ra) * DIM_FF + koff;
  const u16* gb1 = gb0 + (size_t)64 * DIM_FF;

  __bf16* lA0 = As + tid * 8;
  __bf16* lA1 = As + (tid + 256) * 8;
  __bf16* lB0 = Bs + tid * 8;
  __bf16* lB1 = Bs + (tid + 256) * 8;

  const int wm = (wave & 1) * 64;
  const int wn = (wave >> 1) * 64;
  const int quad = lane >> 4;
  const int lc = lane & 15;
  const __bf16* Ap = As + (wm + lc) * 32 + quad * 8;
  const __bf16* Bp = Bs + (wn + lc) * 32 + quad * 8;

  f32x4 acc[4][4];
#pragma unroll
  for (int i = 0; i < 4; ++i)
#pragma unroll
    for (int j = 0; j < 4; ++j) acc[i][j] = (f32x4)0.0f;

  for (int kt = 0; kt < DIM_FF / 32; ++kt) {
    gl2lds16(ga0 + kt * 32, lA0);
    gl2lds16(ga1 + kt * 32, lA1);
    gl2lds16(gb0 + kt * 32, lB0);
    gl2lds16(gb1 + kt * 32, lB1);
    __syncthreads();
    bf16x8 af[4], bfr[4];
#pragma unroll
    for (int mi = 0; mi < 4; ++mi) af[mi] = *(const bf16x8*)(Ap + mi * 16 * 32);
#pragma unroll
    for (int ni = 0; ni < 4; ++ni) bfr[ni] = *(const bf16x8*)(Bp + ni * 16 * 32);
#pragma unroll
    for (int mi = 0; mi < 4; ++mi)
#pragma unroll
      for (int ni = 0; ni < 4; ++ni)
        acc[mi][ni] = __builtin_amdgcn_mfma_f32_16x16x32_bf16(af[mi], bfr[ni], acc[mi][ni], 0, 0, 0);
    __syncthreads();
  }

  float bias[4];
#pragma unroll
  for (int ni = 0; ni < 4; ++ni) bias[ni] = b2[e * D_MODEL + ct * 128 + wn + ni * 16 + lc];

  if (use_y) {
#pragma unroll
    for (int mi = 0; mi < 4; ++mi) {
#pragma unroll
      for (int r = 0; r < 4; ++r) {
        int m = wm + mi * 16 + quad * 4 + r;
        int grow = rt * 128 + m;
        if (grow < count) {
          float* yrow = y + (size_t)(base + grow) * D_MODEL + ct * 128 + wn;
#pragma unroll
          for (int ni = 0; ni < 4; ++ni) yrow[ni * 16 + lc] = acc[mi][ni][r] + bias[ni];
        }
      }
    }
  } else {
#pragma unroll
    for (int mi = 0; mi < 4; ++mi) {
#pragma unroll
      for (int r = 0; r < 4; ++r) {
        int m = wm + mi * 16 + quad * 4 + r;
        int grow = rt * 128 + m;
        if (grow < count) {
          int slot = base + grow;
          float wt = rowwt[slot];
          float* orow = out + (size_t)rowtok[slot] * D_MODEL + ct * 128 + wn;
#pragma unroll
          for (int ni = 0; ni < 4; ++ni)
            atomicAdd(orow + ni * 16 + lc, wt * (acc[mi][ni][r] + bias[ni]));
        }
      }
    }
  }
}

// ---------- combine: out[t] = w0*y[s0] + w1*y[s1] ----------
__global__ __launch_bounds__(256) void combine_kernel(
    const float* __restrict__ y, const int* __restrict__ tokslot,
    const float* __restrict__ ew, float* __restrict__ out) {
  int gid = blockIdx.x * 256 + threadIdx.x;  // one float4 per thread
  int t = gid >> 8;
  int c = (gid & 255) * 4;
  int s0 = tokslot[2 * t], s1 = tokslot[2 * t + 1];
  float w0 = ew[2 * t], w1 = ew[2 * t + 1];
  float4 a = *(const float4*)(y + (size_t)s0 * D_MODEL + c);
  float4 bb = *(const float4*)(y + (size_t)s1 * D_MODEL + c);
  float4 o;
  o.x = w0 * a.x + w1 * bb.x;
  o.y = w0 * a.y + w1 * bb.y;
  o.z = w0 * a.z + w1 * bb.z;
  o.w = w0 * a.w + w1 * bb.w;
  *(float4*)(out + (size_t)t * D_MODEL + c) = o;
}

extern "C" void kernel_launch(void* const* d_in, const int* in_sizes, int n_in,
                              void* d_out, int out_size, void* d_ws, size_t ws_size,
                              hipStream_t stream) {
  (void)in_sizes; (void)n_in;
  const float* x  = (const float*)d_in[0];
  const float* Wg = (const float*)d_in[1];
  const float* bg = (const float*)d_in[2];
  const float* W1 = (const float*)d_in[3];
  const float* b1 = (const float*)d_in[4];
  const float* W2 = (const float*)d_in[5];
  const float* b2 = (const float*)d_in[6];
  float* out = (float*)d_out;

  char* ws = (char*)d_ws;
  size_t off = 0;
  int*   counts  = (int*)(ws + 0);
  int*   fill    = (int*)(ws + 64);
  int*   offsets = (int*)(ws + 128);
  off = 4096;
  int*   eidx    = (int*)(ws + off); off += 65536;
  float* ew      = (float*)(ws + off); off += 65536;
  int*   rowtok  = (int*)(ws + off); off += 65536;
  float* rowwt   = (float*)(ws + off); off += 65536;
  int*   tokslot = (int*)(ws + off); off += 65536;
  u16*   xb      = (u16*)(ws + off); off += (size_t)N_TOKENS * D_MODEL * 2;
  u16*   w1t     = (u16*)(ws + off);
  u16*   w2t     = w1t;  // ALIASED: W2 transposed after fc1 finishes reading w1t
  off += (size_t)N_EXPERTS * DIM_FF * D_MODEL * 2;
  u16*   H       = (u16*)(ws + off);
  off += (size_t)(MAX_SLOTS + 128) * DIM_FF * 2;  // +128 rows: unguarded tile reads
  float* y       = (float*)(ws + off);
  size_t need_y  = off + (size_t)MAX_SLOTS * D_MODEL * 4;
  const int use_y = (ws_size >= need_y) ? 1 : 0;

  hipMemsetAsync(ws, 0, 4096, stream);
  if (!use_y) hipMemsetAsync(d_out, 0, (size_t)out_size * sizeof(float), stream);

  gate_kernel<<<N_TOKENS / 4, 256, 0, stream>>>(x, Wg, bg, eidx, ew);
  count_kernel<<<N_TOKENS / 256, 256, 0, stream>>>(eidx, counts);
  scan_kernel<<<1, 64, 0, stream>>>(counts, offsets);
  fill_kernel<<<N_TOKENS / 256, 256, 0, stream>>>(eidx, ew, offsets, fill, rowtok, rowwt, tokslot);
  cvt_x_kernel<<<(N_TOKENS * D_MODEL / 8) / 256, 256, 0, stream>>>(x, xb);
  transpose_cvt<<<dim3(DIM_FF / 64, D_MODEL / 64, N_EXPERTS), 256, 0, stream>>>(W1, w1t, D_MODEL, DIM_FF);
  fc1_kernel<<<N_EXPERTS * (DIM_FF / 128) * 64, 256, 0, stream>>>(xb, w1t, b1, rowtok, offsets, H);
  transpose_cvt<<<dim3(D_MODEL / 64, DIM_FF / 64, N_EXPERTS), 256, 0, stream>>>(W2, w2t, DIM_FF, D_MODEL);
  fc2_kernel<<<N_EXPERTS * (D_MODEL / 128) * 64, 256, 0, stream>>>(H, w2t, b2, rowtok, rowwt, offsets, y, out, use_y);
  if (use_y)
    combine_kernel<<<(N_TOKENS * D_MODEL / 4) / 256, 256, 0, stream>>>(y, tokslot, ew, out);
}

// Round 4
// 781.451 us; speedup vs baseline: 1.4138x; 1.0013x over previous
//
#include <hip/hip_runtime.h>
#include <cstdint>

typedef unsigned short u16;
typedef unsigned int u32;

#define N_TOKENS 8192
#define D_MODEL 1024
#define DIM_FF 4096
#define N_EXPERTS 8
#define MAX_SLOTS (N_TOKENS * 2)

typedef __bf16 bf16x8 __attribute__((ext_vector_type(8)));
typedef float f32x4 __attribute__((ext_vector_type(4)));

// ---------- helpers ----------
__device__ __forceinline__ u16 f2bf(float f) {
  u32 u = __float_as_uint(f);
  u32 r = (u + 0x7FFFu + ((u >> 16) & 1u)) >> 16;  // RNE
  return (u16)r;
}

// async global->LDS, 16B per lane; LDS dst = wave-uniform base + lane*16
__device__ __forceinline__ void gl2lds16(const void* g, void* l) {
  __builtin_amdgcn_global_load_lds(
      (__attribute__((address_space(1))) void*)(g),
      (__attribute__((address_space(3))) void*)(l), 16, 0, 0);
}

// ---------- gate: logits -> softmax -> top2 -> renorm (no atomics) ----------
__global__ __launch_bounds__(256) void gate_kernel(
    const float* __restrict__ x, const float* __restrict__ Wg,
    const float* __restrict__ bg, int* __restrict__ eidx,
    float* __restrict__ ew) {
  int tok = (int)((blockIdx.x * 256 + threadIdx.x) >> 6);
  int lane = threadIdx.x & 63;
  const float* xr = x + (size_t)tok * D_MODEL;
  float acc[8] = {0.f, 0.f, 0.f, 0.f, 0.f, 0.f, 0.f, 0.f};
  for (int j = 0; j < 16; ++j) {
    int d = lane + 64 * j;
    float xv = xr[d];
    float4 wa = *(const float4*)(Wg + d * 8);
    float4 wb = *(const float4*)(Wg + d * 8 + 4);
    acc[0] += xv * wa.x; acc[1] += xv * wa.y; acc[2] += xv * wa.z; acc[3] += xv * wa.w;
    acc[4] += xv * wb.x; acc[5] += xv * wb.y; acc[6] += xv * wb.z; acc[7] += xv * wb.w;
  }
#pragma unroll
  for (int off = 32; off > 0; off >>= 1) {
#pragma unroll
    for (int e = 0; e < 8; ++e) acc[e] += __shfl_xor(acc[e], off, 64);
  }
  if (lane == 0) {
    float p[8], m = -1e30f;
#pragma unroll
    for (int e = 0; e < 8; ++e) { p[e] = acc[e] + bg[e]; m = fmaxf(m, p[e]); }
    float s = 0.f;
#pragma unroll
    for (int e = 0; e < 8; ++e) { p[e] = __expf(p[e] - m); s += p[e]; }
#pragma unroll
    for (int e = 0; e < 8; ++e) p[e] /= s;
    int i0 = 0;
#pragma unroll
    for (int e = 1; e < 8; ++e) if (p[e] > p[i0]) i0 = e;
    int i1 = (i0 == 0) ? 1 : 0;
#pragma unroll
    for (int e = 0; e < 8; ++e) if (e != i0 && p[e] > p[i1]) i1 = e;
    float denom = p[i0] + p[i1] + 1e-9f;
    eidx[2 * tok] = i0; eidx[2 * tok + 1] = i1;   // k=0: top-1, k=1: top-2
    ew[2 * tok] = p[i0] / denom; ew[2 * tok + 1] = p[i1] / denom;
  }
}

// ---------- count: per-block LDS histogram over (expert,rank) -> 16 atomics/block ----------
__global__ __launch_bounds__(256) void count_kernel(const int* __restrict__ eidx,
                                                    int* __restrict__ counts) {
  __shared__ int lc[16];
  int tid = threadIdx.x;
  if (tid < 16) lc[tid] = 0;
  __syncthreads();
  int t = blockIdx.x * 256 + tid;
  atomicAdd(&lc[2 * eidx[2 * t]], 1);          // rank 0
  atomicAdd(&lc[2 * eidx[2 * t + 1] + 1], 1);  // rank 1
  __syncthreads();
  if (tid < 16) atomicAdd(&counts[tid], lc[tid]);
}

__global__ void scan_kernel(const int* __restrict__ counts, int* __restrict__ off16) {
  if (threadIdx.x == 0) {
    int o = 0;
    for (int g = 0; g < 16; ++g) { off16[g] = o; o += counts[g]; }
    off16[16] = o;
  }
}

// ---------- fill: block-aggregated range claiming into (expert,rank) subgroups ----------
__global__ __launch_bounds__(256) void fill_kernel(
    const int* __restrict__ eidx, const float* __restrict__ ew,
    const int* __restrict__ off16, int* __restrict__ fill,
    int* __restrict__ rowtok, float* __restrict__ rowwt) {
  __shared__ int lc[16];
  __shared__ int lbase[16];
  int tid = threadIdx.x;
  if (tid < 16) lc[tid] = 0;
  __syncthreads();
  int t = blockIdx.x * 256 + tid;
  int e0 = eidx[2 * t], e1 = eidx[2 * t + 1];
  int p0 = atomicAdd(&lc[2 * e0], 1);
  int p1 = atomicAdd(&lc[2 * e1 + 1], 1);
  __syncthreads();
  if (tid < 16) lbase[tid] = atomicAdd(&fill[tid], lc[tid]);
  __syncthreads();
  int pos0 = off16[2 * e0] + lbase[2 * e0] + p0;
  int pos1 = off16[2 * e1 + 1] + lbase[2 * e1 + 1] + p1;
  rowtok[pos0] = t; rowwt[pos0] = ew[2 * t];
  rowtok[pos1] = t; rowwt[pos1] = ew[2 * t + 1];
}

// ---------- fp32 -> bf16 copy of x ----------
__global__ __launch_bounds__(256) void cvt_x_kernel(const float* __restrict__ in,
                                                    u16* __restrict__ out) {
  size_t t = (size_t)blockIdx.x * 256 + threadIdx.x;  // 8 elements per thread
  const float4* ip = (const float4*)in + t * 2;
  float4 a = ip[0], b = ip[1];
  uint4 o;
  o.x = f2bf(a.x) | ((u32)f2bf(a.y) << 16);
  o.y = f2bf(a.z) | ((u32)f2bf(a.w) << 16);
  o.z = f2bf(b.x) | ((u32)f2bf(b.y) << 16);
  o.w = f2bf(b.z) | ((u32)f2bf(b.w) << 16);
  *((uint4*)out + t) = o;
}

// ---------- per-expert transpose+convert: in [R][C] fp32 -> out [C][R] bf16 ----------
// 128 rows x 64 cols per block: 256B-contiguous global reads AND writes.
__global__ __launch_bounds__(256) void transpose_cvt(const float* __restrict__ in,
                                                     u16* __restrict__ out, int R, int C) {
  int e = blockIdx.z;
  const float* ip = in + (size_t)e * R * C;
  u16* op = out + (size_t)e * R * C;
  int c0 = blockIdx.x * 64, r0 = blockIdx.y * 128;
  __shared__ __align__(16) u16 t[64 * 136];  // [c][r], stride 136 u16 = 272 B
  int tid = threadIdx.x;
  int j4 = (tid & 15) * 4;
#pragma unroll
  for (int p = 0; p < 8; ++p) {
    int i = (tid >> 4) + 16 * p;
    float4 v = *(const float4*)(ip + (size_t)(r0 + i) * C + c0 + j4);
    t[(j4 + 0) * 136 + i] = f2bf(v.x);
    t[(j4 + 1) * 136 + i] = f2bf(v.y);
    t[(j4 + 2) * 136 + i] = f2bf(v.z);
    t[(j4 + 3) * 136 + i] = f2bf(v.w);
  }
  __syncthreads();
  int i8 = (tid & 15) * 8;
#pragma unroll
  for (int p = 0; p < 4; ++p) {
    int c = (tid >> 4) + 16 * p;
    uint4 val = *(const uint4*)&t[c * 136 + i8];
    *(uint4*)(op + (size_t)(c0 + c) * R + r0 + i8) = val;  // 16 lanes = 256B contiguous
  }
}

// ---------- fc1: H[slot,f] = gelu(Xg @ W1 + b1), bf16 ----------
// 1-D grid, XCD swizzle: expert = b&7 (pins expert to XCD), rt-fast within expert.
__global__ __launch_bounds__(256) void fc1_kernel(
    const u16* __restrict__ xb, const u16* __restrict__ w1t,
    const float* __restrict__ b1, const int* __restrict__ rowtok,
    const int* __restrict__ off16, u16* __restrict__ H) {
  const int b = blockIdx.x;
  const int e = b & 7;
  const int lin = b >> 3;      // 0..2047
  const int rt = lin & 63;     // rt-fast: consecutive active blocks share B col
  const int ct = lin >> 6;     // 0..31
  const int base = off16[2 * e];
  const int count = off16[2 * e + 2] - base;   // whole-expert (both ranks)
  if (rt * 128 >= count) return;

  __shared__ __align__(16) __bf16 As[128 * 32];
  __shared__ __align__(16) __bf16 Bs[128 * 32];

  const int tid = threadIdx.x;
  const int lane = tid & 63;
  const int wave = tid >> 6;

  const int ra = tid >> 2;  // chunk row 0..63 (pass0); +64 pass1
  const int lastslot = base + count - 1;
  int s0 = base + rt * 128 + ra;       if (s0 > lastslot) s0 = lastslot;
  int s1 = base + rt * 128 + ra + 64;  if (s1 > lastslot) s1 = lastslot;
  const size_t koff = (size_t)(tid & 3) * 8;
  const u16* ga0 = xb + (size_t)rowtok[s0] * D_MODEL + koff;
  const u16* ga1 = xb + (size_t)rowtok[s1] * D_MODEL + koff;
  const u16* gb0 = w1t + (size_t)e * DIM_FF * D_MODEL + (size_t)(ct * 128 + ra) * D_MODEL + koff;
  const u16* gb1 = gb0 + (size_t)64 * D_MODEL;

  __bf16* lA0 = As + tid * 8;
  __bf16* lA1 = As + (tid + 256) * 8;
  __bf16* lB0 = Bs + tid * 8;
  __bf16* lB1 = Bs + (tid + 256) * 8;

  const int wm = (wave & 1) * 64;
  const int wn = (wave >> 1) * 64;
  const int quad = lane >> 4;
  const int lc = lane & 15;
  const __bf16* Ap = As + (wm + lc) * 32 + quad * 8;
  const __bf16* Bp = Bs + (wn + lc) * 32 + quad * 8;

  f32x4 acc[4][4];
#pragma unroll
  for (int i = 0; i < 4; ++i)
#pragma unroll
    for (int j = 0; j < 4; ++j) acc[i][j] = (f32x4)0.0f;

  for (int kt = 0; kt < D_MODEL / 32; ++kt) {
    gl2lds16(ga0 + kt * 32, lA0);
    gl2lds16(ga1 + kt * 32, lA1);
    gl2lds16(gb0 + kt * 32, lB0);
    gl2lds16(gb1 + kt * 32, lB1);
    __syncthreads();
    bf16x8 af[4], bfr[4];
#pragma unroll
    for (int mi = 0; mi < 4; ++mi) af[mi] = *(const bf16x8*)(Ap + mi * 16 * 32);
#pragma unroll
    for (int ni = 0; ni < 4; ++ni) bfr[ni] = *(const bf16x8*)(Bp + ni * 16 * 32);
#pragma unroll
    for (int mi = 0; mi < 4; ++mi)
#pragma unroll
      for (int ni = 0; ni < 4; ++ni)
        acc[mi][ni] = __builtin_amdgcn_mfma_f32_16x16x32_bf16(af[mi], bfr[ni], acc[mi][ni], 0, 0, 0);
    __syncthreads();
  }

  float bias[4];
#pragma unroll
  for (int ni = 0; ni < 4; ++ni) bias[ni] = b1[e * DIM_FF + ct * 128 + wn + ni * 16 + lc];
#pragma unroll
  for (int mi = 0; mi < 4; ++mi) {
#pragma unroll
    for (int r = 0; r < 4; ++r) {
      int m = wm + mi * 16 + quad * 4 + r;
      int grow = rt * 128 + m;
      if (grow < count) {
        size_t rowbase = (size_t)(base + grow) * DIM_FF + ct * 128 + wn;
#pragma unroll
        for (int ni = 0; ni < 4; ++ni) {
          float v = acc[mi][ni][r] + bias[ni];
          // tanh-form GELU via exp2+rcp; max abs err ~3e-4 (<< bf16 rounding of H)
          float t3 = v * (1.0f + 0.044715f * v * v);
          float u = __builtin_amdgcn_exp2f(fminf(2.302208f * t3, 80.0f));
          float h = v * u * __builtin_amdgcn_rcpf(u + 1.0f);
          H[rowbase + ni * 16 + lc] = f2bf(h);
        }
      }
    }
  }
}

// ---------- fc2: pass kpass=0 (top-1 slots): out[tok] = wt*(H@W2 + b2) plain store
//             pass kpass=1 (top-2 slots): out[tok] += wt*(...)  plain RMW (race-free:
//             each token appears exactly once per rank; kernel boundary orders passes)
__global__ __launch_bounds__(256) void fc2_kernel(
    const u16* __restrict__ H, const u16* __restrict__ w2t,
    const float* __restrict__ b2, const int* __restrict__ rowtok,
    const float* __restrict__ rowwt, const int* __restrict__ off16,
    float* __restrict__ out, int kpass) {
  const int b = blockIdx.x;
  const int e = b & 7;
  const int lin = b >> 3;      // 0..511
  const int rt = lin & 63;
  const int ct = lin >> 6;     // 0..7
  const int base = off16[2 * e + kpass];
  const int cnt  = off16[2 * e + kpass + 1] - base;
  if (rt * 128 >= cnt) return;

  __shared__ __align__(16) __bf16 As[128 * 32];
  __shared__ __align__(16) __bf16 Bs[128 * 32];

  const int tid = threadIdx.x;
  const int lane = tid & 63;
  const int wave = tid >> 6;

  const int ra = tid >> 2;
  const size_t koff = (size_t)(tid & 3) * 8;
  const u16* ga0 = H + (size_t)(base + rt * 128 + ra) * DIM_FF + koff;  // contiguous slots
  const u16* ga1 = ga0 + (size_t)64 * DIM_FF;
  const u16* gb0 = w2t + (size_t)e * D_MODEL * DIM_FF + (size_t)(ct * 128 + ra) * DIM_FF + koff;
  const u16* gb1 = gb0 + (size_t)64 * DIM_FF;

  __bf16* lA0 = As + tid * 8;
  __bf16* lA1 = As + (tid + 256) * 8;
  __bf16* lB0 = Bs + tid * 8;
  __bf16* lB1 = Bs + (tid + 256) * 8;

  const int wm = (wave & 1) * 64;
  const int wn = (wave >> 1) * 64;
  const int quad = lane >> 4;
  const int lc = lane & 15;
  const __bf16* Ap = As + (wm + lc) * 32 + quad * 8;
  const __bf16* Bp = Bs + (wn + lc) * 32 + quad * 8;

  f32x4 acc[4][4];
#pragma unroll
  for (int i = 0; i < 4; ++i)
#pragma unroll
    for (int j = 0; j < 4; ++j) acc[i][j] = (f32x4)0.0f;

  for (int kt = 0; kt < DIM_FF / 32; ++kt) {
    gl2lds16(ga0 + kt * 32, lA0);
    gl2lds16(ga1 + kt * 32, lA1);
    gl2lds16(gb0 + kt * 32, lB0);
    gl2lds16(gb1 + kt * 32, lB1);
    __syncthreads();
    bf16x8 af[4], bfr[4];
#pragma unroll
    for (int mi = 0; mi < 4; ++mi) af[mi] = *(const bf16x8*)(Ap + mi * 16 * 32);
#pragma unroll
    for (int ni = 0; ni < 4; ++ni) bfr[ni] = *(const bf16x8*)(Bp + ni * 16 * 32);
#pragma unroll
    for (int mi = 0; mi < 4; ++mi)
#pragma unroll
      for (int ni = 0; ni < 4; ++ni)
        acc[mi][ni] = __builtin_amdgcn_mfma_f32_16x16x32_bf16(af[mi], bfr[ni], acc[mi][ni], 0, 0, 0);
    __syncthreads();
  }

  float bias[4];
#pragma unroll
  for (int ni = 0; ni < 4; ++ni) bias[ni] = b2[e * D_MODEL + ct * 128 + wn + ni * 16 + lc];

#pragma unroll
  for (int mi = 0; mi < 4; ++mi) {
#pragma unroll
    for (int r = 0; r < 4; ++r) {
      int m = wm + mi * 16 + quad * 4 + r;
      int grow = rt * 128 + m;
      if (grow < cnt) {
        int slot = base + grow;
        float wt = rowwt[slot];
        float* orow = out + (size_t)rowtok[slot] * D_MODEL + ct * 128 + wn;
        if (kpass == 0) {
#pragma unroll
          for (int ni = 0; ni < 4; ++ni)
            orow[ni * 16 + lc] = wt * (acc[mi][ni][r] + bias[ni]);
        } else {
#pragma unroll
          for (int ni = 0; ni < 4; ++ni)
            orow[ni * 16 + lc] += wt * (acc[mi][ni][r] + bias[ni]);
        }
      }
    }
  }
}

extern "C" void kernel_launch(void* const* d_in, const int* in_sizes, int n_in,
                              void* d_out, int out_size, void* d_ws, size_t ws_size,
                              hipStream_t stream) {
  (void)in_sizes; (void)n_in; (void)ws_size; (void)out_size;
  const float* x  = (const float*)d_in[0];
  const float* Wg = (const float*)d_in[1];
  const float* bg = (const float*)d_in[2];
  const float* W1 = (const float*)d_in[3];
  const float* b1 = (const float*)d_in[4];
  const float* W2 = (const float*)d_in[5];
  const float* b2 = (const float*)d_in[6];
  float* out = (float*)d_out;

  char* ws = (char*)d_ws;
  size_t off = 0;
  int*   counts  = (int*)(ws + 0);     // 16 ints
  int*   fill    = (int*)(ws + 128);   // 16 ints
  int*   off16   = (int*)(ws + 256);   // 17 ints
  off = 4096;
  int*   eidx    = (int*)(ws + off); off += 65536;
  float* ew      = (float*)(ws + off); off += 65536;
  int*   rowtok  = (int*)(ws + off); off += 65536;
  float* rowwt   = (float*)(ws + off); off += 65536;
  u16*   xb      = (u16*)(ws + off); off += (size_t)N_TOKENS * D_MODEL * 2;
  u16*   w1t     = (u16*)(ws + off);
  u16*   w2t     = w1t;  // ALIASED: W2 transposed after fc1 finishes reading w1t
  off += (size_t)N_EXPERTS * DIM_FF * D_MODEL * 2;
  u16*   H       = (u16*)(ws + off);
  off += (size_t)(MAX_SLOTS + 128) * DIM_FF * 2;  // +128 rows: unguarded tail reads
  // total ~216 MB

  hipMemsetAsync(ws, 0, 4096, stream);

  gate_kernel<<<N_TOKENS / 4, 256, 0, stream>>>(x, Wg, bg, eidx, ew);
  count_kernel<<<N_TOKENS / 256, 256, 0, stream>>>(eidx, counts);
  scan_kernel<<<1, 64, 0, stream>>>(counts, off16);
  fill_kernel<<<N_TOKENS / 256, 256, 0, stream>>>(eidx, ew, off16, fill, rowtok, rowwt);
  cvt_x_kernel<<<(N_TOKENS * D_MODEL / 8) / 256, 256, 0, stream>>>(x, xb);
  transpose_cvt<<<dim3(DIM_FF / 64, D_MODEL / 128, N_EXPERTS), 256, 0, stream>>>(W1, w1t, D_MODEL, DIM_FF);
  fc1_kernel<<<N_EXPERTS * (DIM_FF / 128) * 64, 256, 0, stream>>>(xb, w1t, b1, rowtok, off16, H);
  transpose_cvt<<<dim3(D_MODEL / 64, DIM_FF / 128, N_EXPERTS), 256, 0, stream>>>(W2, w2t, DIM_FF, D_MODEL);
  fc2_kernel<<<N_EXPERTS * (D_MODEL / 128) * 64, 256, 0, stream>>>(H, w2t, b2, rowtok, rowwt, off16, out, 0);
  fc2_kernel<<<N_EXPERTS * (D_MODEL / 128) * 64, 256, 0, stream>>>(H, w2t, b2, rowtok, rowwt, off16, out, 1);
}

// Round 5
// 775.798 us; speedup vs baseline: 1.4241x; 1.0073x over previous
//
#include <hip/hip_runtime.h>
#include <cstdint>

typedef unsigned short u16;
typedef unsigned int u32;

#define N_TOKENS 8192
#define D_MODEL 1024
#define DIM_FF 4096
#define N_EXPERTS 8
#define MAX_SLOTS (N_TOKENS * 2)

typedef __bf16 bf16x8 __attribute__((ext_vector_type(8)));
typedef float f32x4 __attribute__((ext_vector_type(4)));

// ---------- helpers ----------
__device__ __forceinline__ u16 f2bf(float f) {
  u32 u = __float_as_uint(f);
  u32 r = (u + 0x7FFFu + ((u >> 16) & 1u)) >> 16;  // RNE
  return (u16)r;
}
__device__ __forceinline__ u16 bfc(float f) {  // native cvt (RNE), 1 VALU op
  __bf16 b = (__bf16)f;
  return __builtin_bit_cast(u16, b);
}

// async global->LDS, 16B per lane; LDS dst = wave-uniform base + lane*16
__device__ __forceinline__ void gl2lds16(const void* g, void* l) {
  __builtin_amdgcn_global_load_lds(
      (__attribute__((address_space(1))) void*)(g),
      (__attribute__((address_space(3))) void*)(l), 16, 0, 0);
}

// ---------- gate (+ fused x->bf16 cvt): logits -> softmax -> top2 -> renorm ----------
__global__ __launch_bounds__(256) void gate_kernel(
    const float* __restrict__ x, const float* __restrict__ Wg,
    const float* __restrict__ bg, int* __restrict__ eidx,
    float* __restrict__ ew, u16* __restrict__ xb) {
  int tok = (int)((blockIdx.x * 256 + threadIdx.x) >> 6);
  int lane = threadIdx.x & 63;
  const float* xr = x + (size_t)tok * D_MODEL;
  u16* xbr = xb + (size_t)tok * D_MODEL;
  float acc[8] = {0.f, 0.f, 0.f, 0.f, 0.f, 0.f, 0.f, 0.f};
#pragma unroll
  for (int j = 0; j < 8; ++j) {
    int d = 2 * lane + 128 * j;
    float2 xv = *(const float2*)(xr + d);
    float4 wa0 = *(const float4*)(Wg + d * 8);
    float4 wb0 = *(const float4*)(Wg + d * 8 + 4);
    float4 wa1 = *(const float4*)(Wg + d * 8 + 8);
    float4 wb1 = *(const float4*)(Wg + d * 8 + 12);
    acc[0] += xv.x * wa0.x + xv.y * wa1.x;
    acc[1] += xv.x * wa0.y + xv.y * wa1.y;
    acc[2] += xv.x * wa0.z + xv.y * wa1.z;
    acc[3] += xv.x * wa0.w + xv.y * wa1.w;
    acc[4] += xv.x * wb0.x + xv.y * wb1.x;
    acc[5] += xv.x * wb0.y + xv.y * wb1.y;
    acc[6] += xv.x * wb0.z + xv.y * wb1.z;
    acc[7] += xv.x * wb0.w + xv.y * wb1.w;
    u32 pk = (u32)f2bf(xv.x) | ((u32)f2bf(xv.y) << 16);
    *(u32*)(xbr + d) = pk;  // lanes consecutive -> coalesced 256B/wave
  }
#pragma unroll
  for (int off = 32; off > 0; off >>= 1) {
#pragma unroll
    for (int e = 0; e < 8; ++e) acc[e] += __shfl_xor(acc[e], off, 64);
  }
  if (lane == 0) {
    float p[8], m = -1e30f;
#pragma unroll
    for (int e = 0; e < 8; ++e) { p[e] = acc[e] + bg[e]; m = fmaxf(m, p[e]); }
    float s = 0.f;
#pragma unroll
    for (int e = 0; e < 8; ++e) { p[e] = __expf(p[e] - m); s += p[e]; }
#pragma unroll
    for (int e = 0; e < 8; ++e) p[e] /= s;
    int i0 = 0;
#pragma unroll
    for (int e = 1; e < 8; ++e) if (p[e] > p[i0]) i0 = e;
    int i1 = (i0 == 0) ? 1 : 0;
#pragma unroll
    for (int e = 0; e < 8; ++e) if (e != i0 && p[e] > p[i1]) i1 = e;
    float denom = p[i0] + p[i1] + 1e-9f;
    eidx[2 * tok] = i0; eidx[2 * tok + 1] = i1;   // k=0: top-1, k=1: top-2
    ew[2 * tok] = p[i0] / denom; ew[2 * tok + 1] = p[i1] / denom;
  }
}

// ---------- count: per-block LDS histogram over (expert,rank) -> 16 atomics/block ----------
__global__ __launch_bounds__(256) void count_kernel(const int* __restrict__ eidx,
                                                    int* __restrict__ counts) {
  __shared__ int lc[16];
  int tid = threadIdx.x;
  if (tid < 16) lc[tid] = 0;
  __syncthreads();
  int t = blockIdx.x * 256 + tid;
  atomicAdd(&lc[2 * eidx[2 * t]], 1);          // rank 0
  atomicAdd(&lc[2 * eidx[2 * t + 1] + 1], 1);  // rank 1
  __syncthreads();
  if (tid < 16) atomicAdd(&counts[tid], lc[tid]);
}

// ---------- fill: block-aggregated range claiming; prefix recomputed locally ----------
__global__ __launch_bounds__(256) void fill_kernel(
    const int* __restrict__ eidx, const float* __restrict__ ew,
    const int* __restrict__ counts, int* __restrict__ fill,
    int* __restrict__ rowtok, float* __restrict__ rowwt) {
  __shared__ int lc[16];
  __shared__ int lbase[16];
  __shared__ int loff[16];
  int tid = threadIdx.x;
  if (tid < 16) lc[tid] = 0;
  __syncthreads();
  int t = blockIdx.x * 256 + tid;
  int e0 = eidx[2 * t], e1 = eidx[2 * t + 1];
  int p0 = atomicAdd(&lc[2 * e0], 1);
  int p1 = atomicAdd(&lc[2 * e1 + 1], 1);
  __syncthreads();
  if (tid < 16) lbase[tid] = atomicAdd(&fill[tid], lc[tid]);
  if (tid == 64) {  // different wave than the atomics: runs concurrently
    int o = 0;
    for (int g = 0; g < 16; ++g) { loff[g] = o; o += counts[g]; }
  }
  __syncthreads();
  int pos0 = loff[2 * e0] + lbase[2 * e0] + p0;
  int pos1 = loff[2 * e1 + 1] + lbase[2 * e1 + 1] + p1;
  rowtok[pos0] = t; rowwt[pos0] = ew[2 * t];
  rowtok[pos1] = t; rowwt[pos1] = ew[2 * t + 1];
}

// ---------- per-expert transpose+convert: in [R][C] fp32 -> out [C][R] bf16 ----------
// 64x64 tile. Stage1: native rows into LDS via packed b64 writes (native cvt).
// Stage2: paired ds_read_b32 + lo/hi repack -> two 16B row stores. VALU-light.
__global__ __launch_bounds__(256) void transpose_cvt(const float* __restrict__ in,
                                                     u16* __restrict__ out, int R, int C) {
  int e = blockIdx.z;
  const float* ip = in + (size_t)e * R * C;
  u16* op = out + (size_t)e * R * C;
  int c0 = blockIdx.x * 64, r0 = blockIdx.y * 64;
  __shared__ __align__(16) u16 t[64 * 68];  // [r][c], pitch 68 u16 = 136 B (8B-mult)
  int tid = threadIdx.x;
  int c4 = (tid & 15) * 4;
#pragma unroll
  for (int p = 0; p < 4; ++p) {
    int r = (tid >> 4) + 16 * p;
    float4 v = *(const float4*)(ip + (size_t)(r0 + r) * C + c0 + c4);
    uint2 pk;
    pk.x = (u32)bfc(v.x) | ((u32)bfc(v.y) << 16);
    pk.y = (u32)bfc(v.z) | ((u32)bfc(v.w) << 16);
    *(uint2*)&t[r * 68 + c4] = pk;
  }
  __syncthreads();
  int pair = tid >> 3;        // 0..31 -> output row pair (c, c+1)
  int r8 = (tid & 7) * 8;     // 8 lanes * 16B = 128B contiguous stores
  int c = 2 * pair;
  u32 u[8];
#pragma unroll
  for (int j = 0; j < 8; ++j) u[j] = *(const u32*)&t[(r8 + j) * 68 + c];
  uint4 lo, hi;
  lo.x = (u[0] & 0xffffu) | (u[1] << 16);
  lo.y = (u[2] & 0xffffu) | (u[3] << 16);
  lo.z = (u[4] & 0xffffu) | (u[5] << 16);
  lo.w = (u[6] & 0xffffu) | (u[7] << 16);
  hi.x = (u[0] >> 16) | (u[1] & 0xffff0000u);
  hi.y = (u[2] >> 16) | (u[3] & 0xffff0000u);
  hi.z = (u[4] >> 16) | (u[5] & 0xffff0000u);
  hi.w = (u[6] >> 16) | (u[7] & 0xffff0000u);
  *(uint4*)(op + (size_t)(c0 + c) * R + r0 + r8) = lo;
  *(uint4*)(op + (size_t)(c0 + c + 1) * R + r0 + r8) = hi;
}

// ---------- fc1: H[slot,f] = gelu(Xg @ W1 + b1), bf16 ----------
// 1-D grid, XCD swizzle: expert = b&7 (pins expert to XCD), rt-fast within expert.
__global__ __launch_bounds__(256) void fc1_kernel(
    const u16* __restrict__ xb, const u16* __restrict__ w1t,
    const float* __restrict__ b1, const int* __restrict__ rowtok,
    const int* __restrict__ counts, u16* __restrict__ H) {
  const int b = blockIdx.x;
  const int e = b & 7;
  const int lin = b >> 3;      // 0..2047
  const int rt = lin & 63;     // rt-fast: consecutive active blocks share B col
  const int ct = lin >> 6;     // 0..31
  int base = 0;
#pragma unroll
  for (int g = 0; g < 16; ++g) base += (g < 2 * e) ? counts[g] : 0;
  const int count = counts[2 * e] + counts[2 * e + 1];
  if (rt * 128 >= count) return;

  __shared__ __align__(16) __bf16 As[128 * 32];
  __shared__ __align__(16) __bf16 Bs[128 * 32];

  const int tid = threadIdx.x;
  const int lane = tid & 63;
  const int wave = tid >> 6;

  const int ra = tid >> 2;  // chunk row 0..63 (pass0); +64 pass1
  const int lastslot = base + count - 1;
  int s0 = base + rt * 128 + ra;       if (s0 > lastslot) s0 = lastslot;
  int s1 = base + rt * 128 + ra + 64;  if (s1 > lastslot) s1 = lastslot;
  const size_t koff = (size_t)(tid & 3) * 8;
  const u16* ga0 = xb + (size_t)rowtok[s0] * D_MODEL + koff;
  const u16* ga1 = xb + (size_t)rowtok[s1] * D_MODEL + koff;
  const u16* gb0 = w1t + (size_t)e * DIM_FF * D_MODEL + (size_t)(ct * 128 + ra) * D_MODEL + koff;
  const u16* gb1 = gb0 + (size_t)64 * D_MODEL;

  __bf16* lA0 = As + tid * 8;
  __bf16* lA1 = As + (tid + 256) * 8;
  __bf16* lB0 = Bs + tid * 8;
  __bf16* lB1 = Bs + (tid + 256) * 8;

  const int wm = (wave & 1) * 64;
  const int wn = (wave >> 1) * 64;
  const int quad = lane >> 4;
  const int lc = lane & 15;
  const __bf16* Ap = As + (wm + lc) * 32 + quad * 8;
  const __bf16* Bp = Bs + (wn + lc) * 32 + quad * 8;

  f32x4 acc[4][4];
#pragma unroll
  for (int i = 0; i < 4; ++i)
#pragma unroll
    for (int j = 0; j < 4; ++j) acc[i][j] = (f32x4)0.0f;

  for (int kt = 0; kt < D_MODEL / 32; ++kt) {
    gl2lds16(ga0 + kt * 32, lA0);
    gl2lds16(ga1 + kt * 32, lA1);
    gl2lds16(gb0 + kt * 32, lB0);
    gl2lds16(gb1 + kt * 32, lB1);
    __syncthreads();
    bf16x8 af[4], bfr[4];
#pragma unroll
    for (int mi = 0; mi < 4; ++mi) af[mi] = *(const bf16x8*)(Ap + mi * 16 * 32);
#pragma unroll
    for (int ni = 0; ni < 4; ++ni) bfr[ni] = *(const bf16x8*)(Bp + ni * 16 * 32);
#pragma unroll
    for (int mi = 0; mi < 4; ++mi)
#pragma unroll
      for (int ni = 0; ni < 4; ++ni)
        acc[mi][ni] = __builtin_amdgcn_mfma_f32_16x16x32_bf16(af[mi], bfr[ni], acc[mi][ni], 0, 0, 0);
    __syncthreads();
  }

  float bias[4];
#pragma unroll
  for (int ni = 0; ni < 4; ++ni) bias[ni] = b1[e * DIM_FF + ct * 128 + wn + ni * 16 + lc];
#pragma unroll
  for (int mi = 0; mi < 4; ++mi) {
#pragma unroll
    for (int r = 0; r < 4; ++r) {
      int m = wm + mi * 16 + quad * 4 + r;
      int grow = rt * 128 + m;
      if (grow < count) {
        size_t rowbase = (size_t)(base + grow) * DIM_FF + ct * 128 + wn;
#pragma unroll
        for (int ni = 0; ni < 4; ++ni) {
          float v = acc[mi][ni][r] + bias[ni];
          // tanh-form GELU via exp2+rcp; max abs err ~3e-4 (<< bf16 rounding of H)
          float t3 = v * (1.0f + 0.044715f * v * v);
          float u = __builtin_amdgcn_exp2f(fminf(2.302208f * t3, 80.0f));
          float h = v * u * __builtin_amdgcn_rcpf(u + 1.0f);
          H[rowbase + ni * 16 + lc] = f2bf(h);
        }
      }
    }
  }
}

// ---------- fc2: pass kpass=0 (top-1 slots): out[tok] = wt*(H@W2 + b2) plain store
//             pass kpass=1 (top-2 slots): out[tok] += wt*(...)  plain RMW ----------
__global__ __launch_bounds__(256) void fc2_kernel(
    const u16* __restrict__ H, const u16* __restrict__ w2t,
    const float* __restrict__ b2, const int* __restrict__ rowtok,
    const float* __restrict__ rowwt, const int* __restrict__ counts,
    float* __restrict__ out, int kpass) {
  const int b = blockIdx.x;
  const int e = b & 7;
  const int lin = b >> 3;      // 0..511
  const int rt = lin & 63;
  const int ct = lin >> 6;     // 0..7
  int base = 0;
#pragma unroll
  for (int g = 0; g < 16; ++g) base += (g < 2 * e + kpass) ? counts[g] : 0;
  const int cnt = counts[2 * e + kpass];
  if (rt * 128 >= cnt) return;

  __shared__ __align__(16) __bf16 As[128 * 32];
  __shared__ __align__(16) __bf16 Bs[128 * 32];

  const int tid = threadIdx.x;
  const int lane = tid & 63;
  const int wave = tid >> 6;

  const int ra = tid >> 2;
  const size_t koff = (size_t)(tid & 3) * 8;
  const u16* ga0 = H + (size_t)(base + rt * 128 + ra) * DIM_FF + koff;  // contiguous slots
  const u16* ga1 = ga0 + (size_t)64 * DIM_FF;
  const u16* gb0 = w2t + (size_t)e * D_MODEL * DIM_FF + (size_t)(ct * 128 + ra) * DIM_FF + koff;
  const u16* gb1 = gb0 + (size_t)64 * DIM_FF;

  __bf16* lA0 = As + tid * 8;
  __bf16* lA1 = As + (tid + 256) * 8;
  __bf16* lB0 = Bs + tid * 8;
  __bf16* lB1 = Bs + (tid + 256) * 8;

  const int wm = (wave & 1) * 64;
  const int wn = (wave >> 1) * 64;
  const int quad = lane >> 4;
  const int lc = lane & 15;
  const __bf16* Ap = As + (wm + lc) * 32 + quad * 8;
  const __bf16* Bp = Bs + (wn + lc) * 32 + quad * 8;

  f32x4 acc[4][4];
#pragma unroll
  for (int i = 0; i < 4; ++i)
#pragma unroll
    for (int j = 0; j < 4; ++j) acc[i][j] = (f32x4)0.0f;

  for (int kt = 0; kt < DIM_FF / 32; ++kt) {
    gl2lds16(ga0 + kt * 32, lA0);
    gl2lds16(ga1 + kt * 32, lA1);
    gl2lds16(gb0 + kt * 32, lB0);
    gl2lds16(gb1 + kt * 32, lB1);
    __syncthreads();
    bf16x8 af[4], bfr[4];
#pragma unroll
    for (int mi = 0; mi < 4; ++mi) af[mi] = *(const bf16x8*)(Ap + mi * 16 * 32);
#pragma unroll
    for (int ni = 0; ni < 4; ++ni) bfr[ni] = *(const bf16x8*)(Bp + ni * 16 * 32);
#pragma unroll
    for (int mi = 0; mi < 4; ++mi)
#pragma unroll
      for (int ni = 0; ni < 4; ++ni)
        acc[mi][ni] = __builtin_amdgcn_mfma_f32_16x16x32_bf16(af[mi], bfr[ni], acc[mi][ni], 0, 0, 0);
    __syncthreads();
  }

  float bias[4];
#pragma unroll
  for (int ni = 0; ni < 4; ++ni) bias[ni] = b2[e * D_MODEL + ct * 128 + wn + ni * 16 + lc];

#pragma unroll
  for (int mi = 0; mi < 4; ++mi) {
#pragma unroll
    for (int r = 0; r < 4; ++r) {
      int m = wm + mi * 16 + quad * 4 + r;
      int grow = rt * 128 + m;
      if (grow < cnt) {
        int slot = base + grow;
        float wt = rowwt[slot];
        float* orow = out + (size_t)rowtok[slot] * D_MODEL + ct * 128 + wn;
        if (kpass == 0) {
#pragma unroll
          for (int ni = 0; ni < 4; ++ni)
            orow[ni * 16 + lc] = wt * (acc[mi][ni][r] + bias[ni]);
        } else {
#pragma unroll
          for (int ni = 0; ni < 4; ++ni)
            orow[ni * 16 + lc] += wt * (acc[mi][ni][r] + bias[ni]);
        }
      }
    }
  }
}

extern "C" void kernel_launch(void* const* d_in, const int* in_sizes, int n_in,
                              void* d_out, int out_size, void* d_ws, size_t ws_size,
                              hipStream_t stream) {
  (void)in_sizes; (void)n_in; (void)ws_size; (void)out_size;
  const float* x  = (const float*)d_in[0];
  const float* Wg = (const float*)d_in[1];
  const float* bg = (const float*)d_in[2];
  const float* W1 = (const float*)d_in[3];
  const float* b1 = (const float*)d_in[4];
  const float* W2 = (const float*)d_in[5];
  const float* b2 = (const float*)d_in[6];
  float* out = (float*)d_out;

  char* ws = (char*)d_ws;
  size_t off = 0;
  int*   counts  = (int*)(ws + 0);     // 16 ints
  int*   fill    = (int*)(ws + 128);   // 16 ints
  off = 4096;
  int*   eidx    = (int*)(ws + off); off += 65536;
  float* ew      = (float*)(ws + off); off += 65536;
  int*   rowtok  = (int*)(ws + off); off += 65536;
  float* rowwt   = (float*)(ws + off); off += 65536;
  u16*   xb      = (u16*)(ws + off); off += (size_t)N_TOKENS * D_MODEL * 2;
  u16*   w1t     = (u16*)(ws + off);
  u16*   w2t     = w1t;  // ALIASED: W2 transposed after fc1 finishes reading w1t
  off += (size_t)N_EXPERTS * DIM_FF * D_MODEL * 2;
  u16*   H       = (u16*)(ws + off);
  off += (size_t)(MAX_SLOTS + 128) * DIM_FF * 2;  // +128 rows: unguarded tail reads
  // total ~216 MB

  hipMemsetAsync(ws, 0, 4096, stream);

  gate_kernel<<<N_TOKENS / 4, 256, 0, stream>>>(x, Wg, bg, eidx, ew, xb);
  count_kernel<<<N_TOKENS / 256, 256, 0, stream>>>(eidx, counts);
  fill_kernel<<<N_TOKENS / 256, 256, 0, stream>>>(eidx, ew, counts, fill, rowtok, rowwt);
  transpose_cvt<<<dim3(DIM_FF / 64, D_MODEL / 64, N_EXPERTS), 256, 0, stream>>>(W1, w1t, D_MODEL, DIM_FF);
  fc1_kernel<<<N_EXPERTS * (DIM_FF / 128) * 64, 256, 0, stream>>>(xb, w1t, b1, rowtok, counts, H);
  transpose_cvt<<<dim3(D_MODEL / 64, DIM_FF / 64, N_EXPERTS), 256, 0, stream>>>(W2, w2t, DIM_FF, D_MODEL);
  fc2_kernel<<<N_EXPERTS * (D_MODEL / 128) * 64, 256, 0, stream>>>(H, w2t, b2, rowtok, rowwt, counts, out, 0);
  fc2_kernel<<<N_EXPERTS * (D_MODEL / 128) * 64, 256, 0, stream>>>(H, w2t, b2, rowtok, rowwt, counts, out, 1);
}